// Round 5
// baseline (609.798 us; speedup 1.0000x reference)
//
#include <hip/hip_runtime.h>
#include <cstdint>
#include <cstddef>

// ---------------------------------------------------------------------------
// Transformer encoder block, bf16 MFMA implementation.
//   x:[2,4096,768] fp32 (+ fp32 weights) -> out fp32 [2,4096,768]
// R12: R11's dbuf/1-barrier attn with the load-placement flaw fixed.
// R11 regressed because prefetch loads issued at loop BOTTOM, right before
// __syncthreads -- the compiler's vmcnt(0) drain at the barrier stalled
// ~400cyc/tile on just-issued loads. Now loads issue at loop TOP (right
// after the barrier), giving them the full compute phase to land; the
// end-of-iter drain is then nearly free (R8's property) while keeping
// 1 barrier/tile + full-tile wave drift (phase decoupling). Two named
// staging regsets (A/B) + 2x unrolled loop keep all indexing static.
// GEMM/LN/convert unchanged from R9/R11.
// ---------------------------------------------------------------------------

#define D_MODEL 768
#define N_HEADS 12
#define D_K     64
#define SEQ     4096
#define BATCH   2
#define M_ROWS  (BATCH * SEQ)   // 8192
#define H_FF    3072
#define LDQKV   2304            // packed QKV row pitch

// 0.125 * log2(e): scores come out of MFMA already in log2 domain
#define QSCALE 0.18033688011112042f

typedef __bf16 bf16_t;
typedef __attribute__((ext_vector_type(8))) __bf16 bf16x8;
typedef __attribute__((ext_vector_type(4))) __bf16 bf16x4;
typedef __attribute__((ext_vector_type(2))) __bf16 bf16x2;
typedef __attribute__((ext_vector_type(4))) float  floatx4;
typedef __attribute__((ext_vector_type(4))) short  short4_t;

union bf16x4_cast { bf16x4 h; short4_t s; };

__device__ __forceinline__ float gelu_exact(float x) {
    return 0.5f * x * (1.0f + erff(x * 0.70710678118654752f));
}

#if __has_builtin(__builtin_amdgcn_exp2f)
#define EXP2F(x) __builtin_amdgcn_exp2f(x)
#else
static __device__ __forceinline__ float EXP2F(float x) {
    float r; asm("v_exp_f32 %0, %1" : "=v"(r) : "v"(x)); return r;
}
#endif

// async global->LDS, 16B per lane, dest = wave-uniform base + lane*16
#define GLL16(gp, lp)                                                         \
    __builtin_amdgcn_global_load_lds(                                         \
        (const __attribute__((address_space(1))) void*)(gp),                  \
        (__attribute__((address_space(3))) void*)(lp), 16, 0, 0)

// -------------------------------- convert ----------------------------------
#define NX_V  (6291456 / 4)    // x: 8192*768
#define NW_V  (589824 / 4)     // 768*768
#define NF_V  (2359296 / 4)    // 3072*768
#define NCONV_V (NX_V + 4 * NW_V + 2 * NF_V)   // 3,342,336 vec4s

__global__ __launch_bounds__(256) void fused_convert_kernel(
    const float* __restrict__ x,  const float* __restrict__ wq,
    const float* __restrict__ wk, const float* __restrict__ wv,
    const float* __restrict__ wo, const float* __restrict__ w1,
    const float* __restrict__ w2,
    bf16_t* __restrict__ xb, bf16_t* __restrict__ wqkvb,
    bf16_t* __restrict__ wob, bf16_t* __restrict__ w1b,
    bf16_t* __restrict__ w2b) {
    const int v = blockIdx.x * 256 + threadIdx.x;
    const float* src; bf16_t* dst; int off; float scale = 1.0f;
    if (v < NX_V)                    { src = x;  dst = xb;              off = v; }
    else if (v < NX_V + NW_V)        { src = wq; dst = wqkvb;           off = v - NX_V; scale = QSCALE; }
    else if (v < NX_V + 2 * NW_V)    { src = wk; dst = wqkvb + 589824;  off = v - NX_V - NW_V; }
    else if (v < NX_V + 3 * NW_V)    { src = wv; dst = wqkvb + 1179648; off = v - NX_V - 2 * NW_V; }
    else if (v < NX_V + 4 * NW_V)    { src = wo; dst = wob;             off = v - NX_V - 3 * NW_V; }
    else if (v < NX_V + 4 * NW_V + NF_V) { src = w1; dst = w1b;         off = v - NX_V - 4 * NW_V; }
    else                             { src = w2; dst = w2b;             off = v - NX_V - 4 * NW_V - NF_V; }
    floatx4 f = *(const floatx4*)&src[(size_t)off * 4];
    bf16x4 o = bf16x4{(bf16_t)(f[0] * scale), (bf16_t)(f[1] * scale),
                      (bf16_t)(f[2] * scale), (bf16_t)(f[3] * scale)};
    *(bf16x4*)&dst[(size_t)off * 4] = o;
}

__global__ __launch_bounds__(256) void pack_bias_kernel(
    const float* __restrict__ bq, const float* __restrict__ bk,
    const float* __restrict__ bv, float* __restrict__ dst) {
    int i = blockIdx.x * 256 + threadIdx.x;
    if (i < 768)       dst[i] = bq[i] * QSCALE;
    else if (i < 1536) dst[i] = bk[i - 768];
    else if (i < 2304) dst[i] = bv[i - 1536];
}

// -------------------------------- GEMM -------------------------------------
// C[m,n] = act( sum_k A[m,k]*W[n,k] + bias[n] ).  128xBN tile, BK=64,
// XOR-swizzled LDS (linear GLL16 dest + inverse-swizzled global source col
// + swizzled read slot -- rule #21 involution). Swapped-operand MFMA:
// lane holds C[n..n+3] at one m -> bf16x4 epilogue stores.
template<int BN>   // 128 or 64
__global__ __launch_bounds__(256) void gemm_lds_kernel(
    const bf16_t* __restrict__ A, const bf16_t* __restrict__ W,
    const float* __restrict__ bias, bf16_t* __restrict__ C,
    int M, int N, int K, int act) {

    __shared__ bf16_t As[128 * 64];
    __shared__ bf16_t Bs[BN * 64];

    const int t    = threadIdx.x;
    const int lane = t & 63;
    const int w    = t >> 6;
    const int lrow = lane & 15;
    const int quad = lane >> 4;
    const int n0   = blockIdx.x * BN;
    const int m0   = blockIdx.y * 128;

    constexpr int MI = (BN == 128) ? 4 : 2;
    constexpr int NB = (BN == 128) ? 4 : 2;        // B-tile GLL chunks/wave
    const int wmo = (BN == 128) ? (w >> 1) * 64 : w * 32;
    const int wno = (BN == 128) ? (w & 1) * 64 : 0;

    // staging: chunk = 8 rows x 128B; source k-column pre-swizzled
    const int srow = lane >> 3;                    // row within chunk (0..7)
    const int scol = ((lane & 7) ^ srow) * 8;      // inverse-swizzled k col
    size_t a_g[4];
#pragma unroll
    for (int i = 0; i < 4; ++i)
        a_g[i] = (size_t)(m0 + (w * 4 + i) * 8 + srow) * K + scol;
    size_t b_g[NB];
#pragma unroll
    for (int i = 0; i < NB; ++i)
        b_g[i] = (size_t)(n0 + (w * NB + i) * 8 + srow) * K + scol;

    // fragment-read swizzle: slot = (kk*4+quad) ^ (row&7), row&7 == lrow&7
    const int slot0 = (quad ^ (lrow & 7)) * 8;     // kk=0, in elements
    const int slot1 = slot0 ^ 32;                  // kk=1 (ks+4 -> ^4 slots)

    floatx4 acc[MI][4];
#pragma unroll
    for (int i = 0; i < MI; ++i)
#pragma unroll
        for (int j = 0; j < 4; ++j) acc[i][j] = floatx4{0.f, 0.f, 0.f, 0.f};

    for (int k0 = 0; k0 < K; k0 += 64) {
#pragma unroll
        for (int i = 0; i < 4; ++i)
            GLL16(&A[a_g[i] + k0], &As[(w * 4 + i) * 512]);
#pragma unroll
        for (int i = 0; i < NB; ++i)
            GLL16(&W[b_g[i] + k0], &Bs[(w * NB + i) * 512]);
        __syncthreads();

#pragma unroll
        for (int kk = 0; kk < 2; ++kk) {
            const int off = kk ? slot1 : slot0;
            bf16x8 a[MI], b[4];
#pragma unroll
            for (int i = 0; i < MI; ++i)
                a[i] = *(bf16x8*)&As[(wmo + i * 16 + lrow) * 64 + off];
#pragma unroll
            for (int j = 0; j < 4; ++j)
                b[j] = *(bf16x8*)&Bs[(wno + j * 16 + lrow) * 64 + off];
#pragma unroll
            for (int i = 0; i < MI; ++i)
#pragma unroll
                for (int j = 0; j < 4; ++j)
                    acc[i][j] = __builtin_amdgcn_mfma_f32_16x16x32_bf16(
                        b[j], a[i], acc[i][j], 0, 0, 0);   // C^T fragment
        }
        __syncthreads();
    }

    // epilogue: lane holds n = quad*4+{0..3} at m = lrow (per i,j tile)
#pragma unroll
    for (int i = 0; i < MI; ++i) {
        const int m = m0 + wmo + i * 16 + lrow;
#pragma unroll
        for (int j = 0; j < 4; ++j) {
            const int n = n0 + wno + j * 16 + quad * 4;
            const floatx4 bv = *(const floatx4*)&bias[n];
            float v0 = acc[i][j][0] + bv[0];
            float v1 = acc[i][j][1] + bv[1];
            float v2 = acc[i][j][2] + bv[2];
            float v3 = acc[i][j][3] + bv[3];
            if (act) {
                v0 = gelu_exact(v0); v1 = gelu_exact(v1);
                v2 = gelu_exact(v2); v3 = gelu_exact(v3);
            }
            *(bf16x4*)&C[(size_t)m * N + n] =
                bf16x4{(bf16_t)v0, (bf16_t)v1, (bf16_t)v2, (bf16_t)v3};
        }
    }
}

// ------------------------------ attention ----------------------------------
// Flash-style, fixed-base softmax, deferred row-sum.
//   S^T = K*Q^T   (k32 MFMA; C-layout: lane holds q=lrow, keys=quad*4+r)
//   P = exp2(S^T) in registers; consumed as B operand of O^T = V^T*P^T (k16).
// R12 pipeline (1 barrier/tile, cheap drains). Iter t (unrolled x2,
// regsets A/B alternate):
//   top:    issue global loads tile t+2 -> regset (full compute to land)
//   middle: compute buf[t&1]
//   bottom: write regset(tile t+1, landed by prev barrier) -> buf[(t+1)&1]
//   barrier (vmcnt drain waits on ~600cyc-old loads: cheap)
// Ordering: barriers totally order iters; within iter t, reads hit buf[t&1],
// writes hit buf[(t+1)&1] -- disjoint. Regs written to LDS in iter t were
// loaded in iter t-1 and guaranteed landed by the end-of-(t-1) drain.
__global__ __launch_bounds__(256, 3) void attn_kernel(
    const bf16_t* __restrict__ QKV, bf16_t* __restrict__ Ctx) {

    __shared__ bf16_t Ks[2][64 * 72];     // 2 x 9216 B  [key][d] pitch 72
    __shared__ bf16_t Vt[2][64 * 72];     // 2 x 9216 B  [d][key^vsw(d)]

    const int t    = threadIdx.x;
    const int lane = t & 63;
    const int w    = t >> 6;
    const int lrow = lane & 15;
    const int quad = lane >> 4;

    const int b  = blockIdx.y / N_HEADS;
    const int h  = blockIdx.y % N_HEADS;
    const int q0 = blockIdx.x * 128 + w * 32;
    const size_t base_q = ((size_t)b * SEQ) * LDQKV + h * D_K;
    const size_t base_k = base_q + 768;
    const size_t base_v = base_q + 1536;
    const size_t base_o = ((size_t)b * SEQ) * D_MODEL + h * D_K;

    // Q fragments (B operand of S^T = K*Q^T: n=q=lane&15, k=d).
    bf16x8 qf[2][2];
#pragma unroll
    for (int s = 0; s < 2; ++s) {
        const size_t qrow = base_q + (size_t)(q0 + s * 16 + lrow) * LDQKV + quad * 8;
        qf[s][0] = *(const bf16x8*)&QKV[qrow];
        qf[s][1] = *(const bf16x8*)&QKV[qrow + 32];
    }

    float l_part[2] = {0.f, 0.f};
    floatx4 o_acc[2][4];
#pragma unroll
    for (int s = 0; s < 2; ++s)
#pragma unroll
        for (int d = 0; d < 4; ++d) o_acc[s][d] = floatx4{0.f, 0.f, 0.f, 0.f};

    // staging assignments
    const int skey = t >> 2;                       // Ks: key 0..63
    const int sch  = t & 3;                        //     d-chunk 0..3
    const int kp   = t >> 3;                       // Vt: key pair 0..31
    const int sch8 = t & 7;                        //     d-chunk-of-8 0..7
    const int vcol = ((2 * kp) & 63) ^ (sch8 << 3);

    const size_t gk0 = base_k + (size_t)skey * LDQKV + sch * 8;
    const size_t gv0 = base_v + (size_t)(2 * kp) * LDQKV + sch8 * 8;

#define ATTN_LOAD(koff, KV0, KV1, VV0, VV1)                                   \
    {                                                                         \
        const size_t gk_ = gk0 + (size_t)(koff) * LDQKV;                      \
        const size_t gv_ = gv0 + (size_t)(koff) * LDQKV;                      \
        KV0 = *(const bf16x8*)&QKV[gk_];                                      \
        KV1 = *(const bf16x8*)&QKV[gk_ + 32];                                 \
        VV0 = *(const bf16x8*)&QKV[gv_];                                      \
        VV1 = *(const bf16x8*)&QKV[gv_ + LDQKV];                              \
    }

#define ATTN_WRITE(BUF, KV0, KV1, VV0, VV1)                                   \
    {                                                                         \
        bf16_t* ksn_ = Ks[BUF];                                               \
        bf16_t* vtn_ = Vt[BUF];                                               \
        *(bf16x8*)&ksn_[skey * 72 + sch * 8]      = KV0;                      \
        *(bf16x8*)&ksn_[skey * 72 + sch * 8 + 32] = KV1;                      \
        _Pragma("unroll")                                                     \
        for (int j = 0; j < 8; ++j)                                           \
            *(bf16x2*)&vtn_[(sch8 * 8 + j) * 72 + vcol] = bf16x2{VV0[j], VV1[j]}; \
    }

#define ATTN_COMPUTE(CUR)                                                     \
    {                                                                         \
        const bf16_t* ks_ = Ks[CUR];                                          \
        const bf16_t* vt_ = Vt[CUR];                                          \
        __builtin_amdgcn_s_setprio(1);                                        \
        short4_t p[2][4];                                                     \
        _Pragma("unroll")                                                     \
        for (int kt = 0; kt < 4; ++kt) {                                      \
            bf16x8 ka0 = *(bf16x8*)&ks_[(kt * 16 + lrow) * 72 + quad * 8];    \
            bf16x8 ka1 = *(bf16x8*)&ks_[(kt * 16 + lrow) * 72 + 32 + quad * 8]; \
            floatx4 z = floatx4{0.f, 0.f, 0.f, 0.f};                          \
            _Pragma("unroll")                                                 \
            for (int s = 0; s < 2; ++s) {                                     \
                floatx4 st = __builtin_amdgcn_mfma_f32_16x16x32_bf16(ka0, qf[s][0], z, 0, 0, 0); \
                st = __builtin_amdgcn_mfma_f32_16x16x32_bf16(ka1, qf[s][1], st, 0, 0, 0); \
                float p0 = EXP2F(st[0]), p1 = EXP2F(st[1]);                   \
                float p2 = EXP2F(st[2]), p3 = EXP2F(st[3]);                   \
                l_part[s] += (p0 + p1) + (p2 + p3);                           \
                bf16x4_cast pc;                                               \
                pc.h = bf16x4{(bf16_t)p0, (bf16_t)p1, (bf16_t)p2, (bf16_t)p3}; \
                p[s][kt] = pc.s;                                              \
            }                                                                 \
        }                                                                     \
        _Pragma("unroll")                                                     \
        for (int dt = 0; dt < 4; ++dt) {                                      \
            const int d_  = dt * 16 + lrow;                                   \
            const int swv = ((d_ >> 3) & 7) << 3;                             \
            _Pragma("unroll")                                                 \
            for (int kc = 0; kc < 4; ++kc) {                                  \
                bf16x4_cast ac;                                               \
                ac.h = *(bf16x4*)&vt_[d_ * 72 + ((kc * 16 + quad * 4) ^ swv)]; \
                o_acc[0][dt] = __builtin_amdgcn_mfma_f32_16x16x16bf16_1k(     \
                    ac.s, p[0][kc], o_acc[0][dt], 0, 0, 0);                   \
                o_acc[1][dt] = __builtin_amdgcn_mfma_f32_16x16x16bf16_1k(     \
                    ac.s, p[1][kc], o_acc[1][dt], 0, 0, 0);                   \
            }                                                                 \
        }                                                                     \
        __builtin_amdgcn_s_setprio(0);                                        \
    }

    // staging regsets A and B (named -> static register allocation)
    bf16x8 akv0, akv1, avv0, avv1;
    bf16x8 bkv0, bkv1, bvv0, bvv1;

    // ---- prologue: tile 0 -> buf0 (through regs); issue tile 1 -> setB ----
    ATTN_LOAD(0, akv0, akv1, avv0, avv1);
    ATTN_WRITE(0, akv0, akv1, avv0, avv1);
    ATTN_LOAD(64, bkv0, bkv1, bvv0, bvv1);
    __syncthreads();   // drains tile-1 loads (startup cost only)

    for (int k0 = 0; k0 < SEQ; k0 += 128) {
        // ---- even sub-iter: compute buf0; setB(tile t+1)->buf1; load->setA
        if (k0 + 128 < SEQ) ATTN_LOAD(k0 + 128, akv0, akv1, avv0, avv1);
        ATTN_COMPUTE(0);
        ATTN_WRITE(1, bkv0, bkv1, bvv0, bvv1);
        __syncthreads();
        // ---- odd sub-iter: compute buf1; setA(tile t+2)->buf0; load->setB
        if (k0 + 192 < SEQ) ATTN_LOAD(k0 + 192, bkv0, bkv1, bvv0, bvv1);
        ATTN_COMPUTE(1);
        if (k0 + 128 < SEQ) ATTN_WRITE(0, akv0, akv1, avv0, avv1);
        __syncthreads();
    }

    // ---- reduce l across quads + normalize + packed b64 stores ----
#pragma unroll
    for (int s = 0; s < 2; ++s) {
        float lsum = l_part[s];
        lsum += __shfl_xor(lsum, 16, 64);
        lsum += __shfl_xor(lsum, 32, 64);
        const float inv = 1.0f / lsum;
        const size_t orow = base_o + (size_t)(q0 + s * 16 + lrow) * D_MODEL;
#pragma unroll
        for (int dt = 0; dt < 4; ++dt) {
            bf16x4 ov = bf16x4{(bf16_t)(o_acc[s][dt][0] * inv),
                               (bf16_t)(o_acc[s][dt][1] * inv),
                               (bf16_t)(o_acc[s][dt][2] * inv),
                               (bf16_t)(o_acc[s][dt][3] * inv)};
            *(bf16x4*)&Ctx[orow + dt * 16 + quad * 4] = ov;
        }
    }
}

// --------------------------- residual + layernorm --------------------------
__global__ __launch_bounds__(256) void ln_res_f32in_kernel(
    const float* __restrict__ x, const bf16_t* __restrict__ res,
    const float* __restrict__ g, const float* __restrict__ be,
    bf16_t* __restrict__ out) {
    const int row = blockIdx.x, t = threadIdx.x;
    const size_t base = (size_t)row * D_MODEL;
    float vals[3], sum = 0.f, sq = 0.f;
#pragma unroll
    for (int it = 0; it < 3; ++it) {
        int i = t + it * 256;
        float v = x[base + i] + (float)res[base + i];
        vals[it] = v; sum += v; sq += v * v;
    }
#pragma unroll
    for (int d = 1; d < 64; d <<= 1) { sum += __shfl_xor(sum, d, 64); sq += __shfl_xor(sq, d, 64); }
    __shared__ float ssum[4], ssq[4], s_mu, s_rs;
    if ((t & 63) == 0) { ssum[t >> 6] = sum; ssq[t >> 6] = sq; }
    __syncthreads();
    if (t == 0) {
        float S = ssum[0] + ssum[1] + ssum[2] + ssum[3];
        float Qq = ssq[0] + ssq[1] + ssq[2] + ssq[3];
        float mu = S / D_MODEL;
        s_mu = mu;
        s_rs = rsqrtf(Qq / D_MODEL - mu * mu + 1e-5f);
    }
    __syncthreads();
    const float mu = s_mu, rs = s_rs;
#pragma unroll
    for (int it = 0; it < 3; ++it) {
        int i = t + it * 256;
        out[base + i] = (bf16_t)((vals[it] - mu) * rs * g[i] + be[i]);
    }
}

__global__ __launch_bounds__(256) void ln_res_final_kernel(
    const bf16_t* __restrict__ a, const bf16_t* __restrict__ bfb,
    const float* __restrict__ g, const float* __restrict__ be,
    float* __restrict__ out) {
    const int row = blockIdx.x, t = threadIdx.x;
    const size_t base = (size_t)row * D_MODEL;
    float vals[3], sum = 0.f, sq = 0.f;
#pragma unroll
    for (int it = 0; it < 3; ++it) {
        int i = t + it * 256;
        float v = (float)a[base + i] + (float)bfb[base + i];
        vals[it] = v; sum += v; sq += v * v;
    }
#pragma unroll
    for (int d = 1; d < 64; d <<= 1) { sum += __shfl_xor(sum, d, 64); sq += __shfl_xor(sq, d, 64); }
    __shared__ float ssum[4], ssq[4], s_mu, s_rs;
    if ((t & 63) == 0) { ssum[t >> 6] = sum; ssq[t >> 6] = sq; }
    __syncthreads();
    if (t == 0) {
        float S = ssum[0] + ssum[1] + ssum[2] + ssum[3];
        float Qq = ssq[0] + ssq[1] + ssq[2] + ssq[3];
        float mu = S / D_MODEL;
        s_mu = mu;
        s_rs = rsqrtf(Qq / D_MODEL - mu * mu + 1e-5f);
    }
    __syncthreads();
    const float mu = s_mu, rs = s_rs;
#pragma unroll
    for (int it = 0; it < 3; ++it) {
        int i = t + it * 256;
        out[base + i] = (vals[it] - mu) * rs * g[i] + be[i];
    }
}

// ------------------------------- launcher ----------------------------------
extern "C" void kernel_launch(void* const* d_in, const int* in_sizes, int n_in,
                              void* d_out, int out_size, void* d_ws, size_t ws_size,
                              hipStream_t stream) {
    const float* x    = (const float*)d_in[0];
    const float* wq   = (const float*)d_in[1];
    const float* bq   = (const float*)d_in[2];
    const float* wk   = (const float*)d_in[3];
    const float* bk   = (const float*)d_in[4];
    const float* wv   = (const float*)d_in[5];
    const float* bv   = (const float*)d_in[6];
    const float* wo   = (const float*)d_in[7];
    const float* bo   = (const float*)d_in[8];
    const float* w1   = (const float*)d_in[9];
    const float* b1   = (const float*)d_in[10];
    const float* w2   = (const float*)d_in[11];
    const float* b2   = (const float*)d_in[12];
    const float* g1   = (const float*)d_in[13];
    const float* be1  = (const float*)d_in[14];
    const float* g2   = (const float*)d_in[15];
    const float* be2  = (const float*)d_in[16];
    float* out = (float*)d_out;

    // ---- workspace layout (aliased; ~127.5 MB) ----
    char* ws = (char*)d_ws;
    const size_t SZ_XB   = (size_t)M_ROWS * D_MODEL * 2;
    const size_t SZ_QKV  = (size_t)M_ROWS * LDQKV * 2;
    const size_t SZ_CTX  = SZ_XB;
    const size_t SZ_H    = (size_t)M_ROWS * H_FF * 2;
    const size_t SZ_WQKV = (size_t)LDQKV * D_MODEL * 2;
    const size_t SZ_WO   = (size_t)D_MODEL * D_MODEL * 2;
    const size_t SZ_W1   = (size_t)H_FF * D_MODEL * 2;

    bf16_t* xb    = (bf16_t*)(ws);                    // also n1 after LN1
    bf16_t* qkvb  = (bf16_t*)(ws + SZ_XB);            // also mha out (reuse)
    bf16_t* ctxb  = (bf16_t*)(ws + SZ_XB + SZ_QKV);   // also ffn2 out (reuse)
    bf16_t* hb    = (bf16_t*)(ws + SZ_XB + SZ_QKV + SZ_CTX);
    char*   wsw   = ws + SZ_XB + SZ_QKV + SZ_CTX + SZ_H;
    bf16_t* wqkvb = (bf16_t*)(wsw);
    bf16_t* wob   = (bf16_t*)(wsw + SZ_WQKV);
    bf16_t* w1b   = (bf16_t*)(wsw + SZ_WQKV + SZ_WO);
    bf16_t* w2b   = (bf16_t*)(wsw + SZ_WQKV + SZ_WO + SZ_W1);
    float*  bqkv  = (float*)(wsw + SZ_WQKV + SZ_WO + 2 * SZ_W1);
    bf16_t* mhab  = qkvb;
    bf16_t* n1b   = xb;
    bf16_t* ffb   = ctxb;

    fused_convert_kernel<<<NCONV_V / 256, 256, 0, stream>>>(
        x, wq, wk, wv, wo, w1, w2, xb, wqkvb, wob, w1b, w2b);
    pack_bias_kernel<<<9, 256, 0, stream>>>(bq, bk, bv, bqkv);

    gemm_lds_kernel<128><<<dim3(LDQKV / 128, M_ROWS / 128), 256, 0, stream>>>(
        xb, wqkvb, bqkv, qkvb, M_ROWS, LDQKV, D_MODEL, 0);

    attn_kernel<<<dim3(SEQ / 128, BATCH * N_HEADS), 256, 0, stream>>>(qkvb, ctxb);

    gemm_lds_kernel<64><<<dim3(D_MODEL / 64, M_ROWS / 128), 256, 0, stream>>>(
        ctxb, wob, bo, mhab, M_ROWS, D_MODEL, D_MODEL, 0);

    ln_res_f32in_kernel<<<M_ROWS, 256, 0, stream>>>(x, mhab, g1, be1, n1b);

    gemm_lds_kernel<128><<<dim3(H_FF / 128, M_ROWS / 128), 256, 0, stream>>>(
        n1b, w1b, b1, hb, M_ROWS, H_FF, D_MODEL, 1);

    gemm_lds_kernel<64><<<dim3(D_MODEL / 64, M_ROWS / 128), 256, 0, stream>>>(
        hb, w2b, b2, ffb, M_ROWS, D_MODEL, H_FF, 0);

    ln_res_final_kernel<<<M_ROWS, 256, 0, stream>>>(n1b, ffb, g2, be2, out);
}

// Round 6
// 474.046 us; speedup vs baseline: 1.2864x; 1.2864x over previous
//
#include <hip/hip_runtime.h>
#include <cstdint>
#include <cstddef>

// ---------------------------------------------------------------------------
// Transformer encoder block, bf16 MFMA implementation.
//   x:[2,4096,768] fp32 (+ fp32 weights) -> out fp32 [2,4096,768]
// R13: third attempt at the 1-barrier dbuf attn, spill surface removed.
// R12 failed on scratch spills (WRITE_SIZE 12MB->383MB: staging regsets +
// 2x-unrolled macro bodies + conditional loads). Fix:
//   - K staging via global_load_lds (zero registers, no ds_write VALU):
//     linear pitch-64 LDS + inverse-swizzled per-lane global source col
//     ((l&7)^(l>>3))*8, fragment read slot (quad^(lrow&7)) -- the GEMM
//     kernel's proven rule-#21 involution, 2-way aliasing = free.
//   - only V register-staged (transpose): 2 x bf16x8 per set, 2 sets.
//   - no loop conditionals: prefetch addrs clamp to last tile (redundant
//     re-loads are L2 hits; redundant last-iter writes hit dead buffers).
// Schedule per iter: {GLL16 K(t+1)->Ks[nxt]; load V(t+2)->regs} | compute
// buf[cur] | {write V(t+1) regs (landed: loaded 1 iter ago) -> Vt[nxt]} |
// barrier. All vmcnt drains wait on >=1-compute-phase-old loads: cheap.
// GEMM/LN/convert unchanged from R9 (best total 483).
// ---------------------------------------------------------------------------

#define D_MODEL 768
#define N_HEADS 12
#define D_K     64
#define SEQ     4096
#define BATCH   2
#define M_ROWS  (BATCH * SEQ)   // 8192
#define H_FF    3072
#define LDQKV   2304            // packed QKV row pitch

// 0.125 * log2(e): scores come out of MFMA already in log2 domain
#define QSCALE 0.18033688011112042f

typedef __bf16 bf16_t;
typedef __attribute__((ext_vector_type(8))) __bf16 bf16x8;
typedef __attribute__((ext_vector_type(4))) __bf16 bf16x4;
typedef __attribute__((ext_vector_type(2))) __bf16 bf16x2;
typedef __attribute__((ext_vector_type(4))) float  floatx4;
typedef __attribute__((ext_vector_type(4))) short  short4_t;

union bf16x4_cast { bf16x4 h; short4_t s; };

__device__ __forceinline__ float gelu_exact(float x) {
    return 0.5f * x * (1.0f + erff(x * 0.70710678118654752f));
}

#if __has_builtin(__builtin_amdgcn_exp2f)
#define EXP2F(x) __builtin_amdgcn_exp2f(x)
#else
static __device__ __forceinline__ float EXP2F(float x) {
    float r; asm("v_exp_f32 %0, %1" : "=v"(r) : "v"(x)); return r;
}
#endif

// async global->LDS, 16B per lane, dest = wave-uniform base + lane*16
#define GLL16(gp, lp)                                                         \
    __builtin_amdgcn_global_load_lds(                                         \
        (const __attribute__((address_space(1))) void*)(gp),                  \
        (__attribute__((address_space(3))) void*)(lp), 16, 0, 0)

// -------------------------------- convert ----------------------------------
#define NX_V  (6291456 / 4)    // x: 8192*768
#define NW_V  (589824 / 4)     // 768*768
#define NF_V  (2359296 / 4)    // 3072*768
#define NCONV_V (NX_V + 4 * NW_V + 2 * NF_V)   // 3,342,336 vec4s

__global__ __launch_bounds__(256) void fused_convert_kernel(
    const float* __restrict__ x,  const float* __restrict__ wq,
    const float* __restrict__ wk, const float* __restrict__ wv,
    const float* __restrict__ wo, const float* __restrict__ w1,
    const float* __restrict__ w2,
    bf16_t* __restrict__ xb, bf16_t* __restrict__ wqkvb,
    bf16_t* __restrict__ wob, bf16_t* __restrict__ w1b,
    bf16_t* __restrict__ w2b) {
    const int v = blockIdx.x * 256 + threadIdx.x;
    const float* src; bf16_t* dst; int off; float scale = 1.0f;
    if (v < NX_V)                    { src = x;  dst = xb;              off = v; }
    else if (v < NX_V + NW_V)        { src = wq; dst = wqkvb;           off = v - NX_V; scale = QSCALE; }
    else if (v < NX_V + 2 * NW_V)    { src = wk; dst = wqkvb + 589824;  off = v - NX_V - NW_V; }
    else if (v < NX_V + 3 * NW_V)    { src = wv; dst = wqkvb + 1179648; off = v - NX_V - 2 * NW_V; }
    else if (v < NX_V + 4 * NW_V)    { src = wo; dst = wob;             off = v - NX_V - 3 * NW_V; }
    else if (v < NX_V + 4 * NW_V + NF_V) { src = w1; dst = w1b;         off = v - NX_V - 4 * NW_V; }
    else                             { src = w2; dst = w2b;             off = v - NX_V - 4 * NW_V - NF_V; }
    floatx4 f = *(const floatx4*)&src[(size_t)off * 4];
    bf16x4 o = bf16x4{(bf16_t)(f[0] * scale), (bf16_t)(f[1] * scale),
                      (bf16_t)(f[2] * scale), (bf16_t)(f[3] * scale)};
    *(bf16x4*)&dst[(size_t)off * 4] = o;
}

__global__ __launch_bounds__(256) void pack_bias_kernel(
    const float* __restrict__ bq, const float* __restrict__ bk,
    const float* __restrict__ bv, float* __restrict__ dst) {
    int i = blockIdx.x * 256 + threadIdx.x;
    if (i < 768)       dst[i] = bq[i] * QSCALE;
    else if (i < 1536) dst[i] = bk[i - 768];
    else if (i < 2304) dst[i] = bv[i - 1536];
}

// -------------------------------- GEMM -------------------------------------
// C[m,n] = act( sum_k A[m,k]*W[n,k] + bias[n] ).  128xBN tile, BK=64,
// XOR-swizzled LDS (linear GLL16 dest + inverse-swizzled global source col
// + swizzled read slot -- rule #21 involution). Swapped-operand MFMA:
// lane holds C[n..n+3] at one m -> bf16x4 epilogue stores.
template<int BN>   // 128 or 64
__global__ __launch_bounds__(256) void gemm_lds_kernel(
    const bf16_t* __restrict__ A, const bf16_t* __restrict__ W,
    const float* __restrict__ bias, bf16_t* __restrict__ C,
    int M, int N, int K, int act) {

    __shared__ bf16_t As[128 * 64];
    __shared__ bf16_t Bs[BN * 64];

    const int t    = threadIdx.x;
    const int lane = t & 63;
    const int w    = t >> 6;
    const int lrow = lane & 15;
    const int quad = lane >> 4;
    const int n0   = blockIdx.x * BN;
    const int m0   = blockIdx.y * 128;

    constexpr int MI = (BN == 128) ? 4 : 2;
    constexpr int NB = (BN == 128) ? 4 : 2;        // B-tile GLL chunks/wave
    const int wmo = (BN == 128) ? (w >> 1) * 64 : w * 32;
    const int wno = (BN == 128) ? (w & 1) * 64 : 0;

    // staging: chunk = 8 rows x 128B; source k-column pre-swizzled
    const int srow = lane >> 3;                    // row within chunk (0..7)
    const int scol = ((lane & 7) ^ srow) * 8;      // inverse-swizzled k col
    size_t a_g[4];
#pragma unroll
    for (int i = 0; i < 4; ++i)
        a_g[i] = (size_t)(m0 + (w * 4 + i) * 8 + srow) * K + scol;
    size_t b_g[NB];
#pragma unroll
    for (int i = 0; i < NB; ++i)
        b_g[i] = (size_t)(n0 + (w * NB + i) * 8 + srow) * K + scol;

    // fragment-read swizzle: slot = (kk*4+quad) ^ (row&7), row&7 == lrow&7
    const int slot0 = (quad ^ (lrow & 7)) * 8;     // kk=0, in elements
    const int slot1 = slot0 ^ 32;                  // kk=1 (ks+4 -> ^4 slots)

    floatx4 acc[MI][4];
#pragma unroll
    for (int i = 0; i < MI; ++i)
#pragma unroll
        for (int j = 0; j < 4; ++j) acc[i][j] = floatx4{0.f, 0.f, 0.f, 0.f};

    for (int k0 = 0; k0 < K; k0 += 64) {
#pragma unroll
        for (int i = 0; i < 4; ++i)
            GLL16(&A[a_g[i] + k0], &As[(w * 4 + i) * 512]);
#pragma unroll
        for (int i = 0; i < NB; ++i)
            GLL16(&W[b_g[i] + k0], &Bs[(w * NB + i) * 512]);
        __syncthreads();

#pragma unroll
        for (int kk = 0; kk < 2; ++kk) {
            const int off = kk ? slot1 : slot0;
            bf16x8 a[MI], b[4];
#pragma unroll
            for (int i = 0; i < MI; ++i)
                a[i] = *(bf16x8*)&As[(wmo + i * 16 + lrow) * 64 + off];
#pragma unroll
            for (int j = 0; j < 4; ++j)
                b[j] = *(bf16x8*)&Bs[(wno + j * 16 + lrow) * 64 + off];
#pragma unroll
            for (int i = 0; i < MI; ++i)
#pragma unroll
                for (int j = 0; j < 4; ++j)
                    acc[i][j] = __builtin_amdgcn_mfma_f32_16x16x32_bf16(
                        b[j], a[i], acc[i][j], 0, 0, 0);   // C^T fragment
        }
        __syncthreads();
    }

    // epilogue: lane holds n = quad*4+{0..3} at m = lrow (per i,j tile)
#pragma unroll
    for (int i = 0; i < MI; ++i) {
        const int m = m0 + wmo + i * 16 + lrow;
#pragma unroll
        for (int j = 0; j < 4; ++j) {
            const int n = n0 + wno + j * 16 + quad * 4;
            const floatx4 bv = *(const floatx4*)&bias[n];
            float v0 = acc[i][j][0] + bv[0];
            float v1 = acc[i][j][1] + bv[1];
            float v2 = acc[i][j][2] + bv[2];
            float v3 = acc[i][j][3] + bv[3];
            if (act) {
                v0 = gelu_exact(v0); v1 = gelu_exact(v1);
                v2 = gelu_exact(v2); v3 = gelu_exact(v3);
            }
            *(bf16x4*)&C[(size_t)m * N + n] =
                bf16x4{(bf16_t)v0, (bf16_t)v1, (bf16_t)v2, (bf16_t)v3};
        }
    }
}

// ------------------------------ attention ----------------------------------
// Flash-style, fixed-base softmax, deferred row-sum.
//   S^T = K*Q^T   (k32 MFMA; C-layout: lane holds q=lrow, keys=quad*4+r)
//   P = exp2(S^T) in registers; consumed as B operand of O^T = V^T*P^T (k16).
// R13 pipeline: 1 barrier/tile, K via GLL16 (XOR-swizzled linear pitch-64),
// V via 2 named regsets, clamped unconditional prefetch. See header comment.
__global__ __launch_bounds__(256, 3) void attn_kernel(
    const bf16_t* __restrict__ QKV, bf16_t* __restrict__ Ctx) {

    __shared__ bf16_t Ks[2][64 * 64];     // 2 x 8192 B, swizzled linear
    __shared__ bf16_t Vt[2][64 * 72];     // 2 x 9216 B, [d][key^vsw(d)]

    const int t    = threadIdx.x;
    const int lane = t & 63;
    const int w    = t >> 6;
    const int lrow = lane & 15;
    const int quad = lane >> 4;

    const int b  = blockIdx.y / N_HEADS;
    const int h  = blockIdx.y % N_HEADS;
    const int q0 = blockIdx.x * 128 + w * 32;
    const size_t base_q = ((size_t)b * SEQ) * LDQKV + h * D_K;
    const size_t base_k = base_q + 768;
    const size_t base_v = base_q + 1536;
    const size_t base_o = ((size_t)b * SEQ) * D_MODEL + h * D_K;

    // Q fragments (B operand of S^T = K*Q^T: n=q=lane&15, k=d).
    bf16x8 qf[2][2];
#pragma unroll
    for (int s = 0; s < 2; ++s) {
        const size_t qrow = base_q + (size_t)(q0 + s * 16 + lrow) * LDQKV + quad * 8;
        qf[s][0] = *(const bf16x8*)&QKV[qrow];
        qf[s][1] = *(const bf16x8*)&QKV[qrow + 32];
    }

    float l_part[2] = {0.f, 0.f};
    floatx4 o_acc[2][4];
#pragma unroll
    for (int s = 0; s < 2; ++s)
#pragma unroll
        for (int d = 0; d < 4; ++d) o_acc[s][d] = floatx4{0.f, 0.f, 0.f, 0.f};

    // ---- K staging via GLL16: wave w stages chunks 2w,2w+1 (8 keys x 128B)
    const int srow  = lane >> 3;                   // 0..7
    const int scolK = ((lane & 7) ^ srow) * 8;     // inverse-swizzled col
    const size_t gkK = base_k + (size_t)(w * 16 + srow) * LDQKV + scolK;
    // fragment read: row = kt*16+lrow, slot = quad^(lrow&7); ka1 = ^32
    const int krd = lrow * 64 + (quad ^ (lrow & 7)) * 8;

#define ATTN_STAGEK(koff, BUF)                                                \
    {                                                                         \
        GLL16(&QKV[gkK + (size_t)(koff) * LDQKV],           &Ks[BUF][(w * 2) * 512]);     \
        GLL16(&QKV[gkK + (size_t)(koff + 8) * LDQKV],       &Ks[BUF][(w * 2 + 1) * 512]); \
    }

    // ---- V staging: 2 keys x 8 d-chunks per thread, 2 named regsets
    const int kp   = t >> 3;                       // key pair 0..31
    const int sch8 = t & 7;                        // d-chunk-of-8 0..7
    const int vcol = ((2 * kp) & 63) ^ (sch8 << 3);
    const size_t gv0 = base_v + (size_t)(2 * kp) * LDQKV + sch8 * 8;

    bf16x8 av0, av1, bv0, bv1;

#define ATTN_LOADV(koff, P)                                                   \
    {                                                                         \
        const size_t gv_ = gv0 + (size_t)(koff) * LDQKV;                      \
        P##v0 = *(const bf16x8*)&QKV[gv_];                                    \
        P##v1 = *(const bf16x8*)&QKV[gv_ + LDQKV];                            \
    }

#define ATTN_WRITEV(BUF, P)                                                   \
    {                                                                         \
        bf16_t* vtn_ = Vt[BUF];                                               \
        _Pragma("unroll")                                                     \
        for (int j = 0; j < 8; ++j)                                           \
            *(bf16x2*)&vtn_[(sch8 * 8 + j) * 72 + vcol] = bf16x2{P##v0[j], P##v1[j]}; \
    }

#define ATTN_COMPUTE(CUR)                                                     \
    {                                                                         \
        const bf16_t* ks_ = Ks[CUR];                                          \
        const bf16_t* vt_ = Vt[CUR];                                          \
        __builtin_amdgcn_s_setprio(1);                                        \
        short4_t p[2][4];                                                     \
        _Pragma("unroll")                                                     \
        for (int kt = 0; kt < 4; ++kt) {                                      \
            bf16x8 ka0 = *(bf16x8*)&ks_[krd + kt * 1024];                     \
            bf16x8 ka1 = *(bf16x8*)&ks_[(krd + kt * 1024) ^ 32];              \
            floatx4 z = floatx4{0.f, 0.f, 0.f, 0.f};                          \
            _Pragma("unroll")                                                 \
            for (int s = 0; s < 2; ++s) {                                     \
                floatx4 st = __builtin_amdgcn_mfma_f32_16x16x32_bf16(ka0, qf[s][0], z, 0, 0, 0); \
                st = __builtin_amdgcn_mfma_f32_16x16x32_bf16(ka1, qf[s][1], st, 0, 0, 0); \
                float p0 = EXP2F(st[0]), p1 = EXP2F(st[1]);                   \
                float p2 = EXP2F(st[2]), p3 = EXP2F(st[3]);                   \
                l_part[s] += (p0 + p1) + (p2 + p3);                           \
                bf16x4_cast pc;                                               \
                pc.h = bf16x4{(bf16_t)p0, (bf16_t)p1, (bf16_t)p2, (bf16_t)p3}; \
                p[s][kt] = pc.s;                                              \
            }                                                                 \
        }                                                                     \
        _Pragma("unroll")                                                     \
        for (int dt = 0; dt < 4; ++dt) {                                      \
            const int d_  = dt * 16 + lrow;                                   \
            const int swv = ((d_ >> 3) & 7) << 3;                             \
            _Pragma("unroll")                                                 \
            for (int kc = 0; kc < 4; ++kc) {                                  \
                bf16x4_cast ac;                                               \
                ac.h = *(bf16x4*)&vt_[d_ * 72 + ((kc * 16 + quad * 4) ^ swv)]; \
                o_acc[0][dt] = __builtin_amdgcn_mfma_f32_16x16x16bf16_1k(     \
                    ac.s, p[0][kc], o_acc[0][dt], 0, 0, 0);                   \
                o_acc[1][dt] = __builtin_amdgcn_mfma_f32_16x16x16bf16_1k(     \
                    ac.s, p[1][kc], o_acc[1][dt], 0, 0, 0);                   \
            }                                                                 \
        }                                                                     \
        __builtin_amdgcn_s_setprio(0);                                        \
    }

    // ---- prologue: K(0)->Ks[0] (GLL); V(0)->setA->Vt[0]; V(64)->setB ----
    ATTN_STAGEK(0, 0);
    ATTN_LOADV(0, a);
    ATTN_WRITEV(0, a);        // compiler waits on setA loads here (one-time)
    ATTN_LOADV(64, b);
    __syncthreads();          // drains K(0) GLL + V(64) loads (startup only)

    for (int k0 = 0; k0 < SEQ; k0 += 128) {
        const int kn2 = (k0 + 128 < SEQ) ? k0 + 128 : SEQ - 64;  // clamp
        const int kn3 = (k0 + 192 < SEQ) ? k0 + 192 : SEQ - 64;  // clamp
        // ---- EVEN: tile k0 from buf0 ----
        ATTN_STAGEK(k0 + 64, 1);       // K(t+1) -> Ks[1], lands by barrier
        ATTN_LOADV(kn2, a);            // V(t+2) -> setA, consumed next iter
        ATTN_COMPUTE(0);
        ATTN_WRITEV(1, b);             // V(t+1) (landed: loaded 1 iter ago)
        __syncthreads();
        // ---- ODD: tile k0+64 from buf1 ----
        ATTN_STAGEK(kn2, 0);           // K(t+2) -> Ks[0]
        ATTN_LOADV(kn3, b);            // V(t+3) -> setB
        ATTN_COMPUTE(1);
        ATTN_WRITEV(0, a);             // V(t+2) -> Vt[0]
        __syncthreads();
    }

    // ---- reduce l across quads + normalize + packed b64 stores ----
#pragma unroll
    for (int s = 0; s < 2; ++s) {
        float lsum = l_part[s];
        lsum += __shfl_xor(lsum, 16, 64);
        lsum += __shfl_xor(lsum, 32, 64);
        const float inv = 1.0f / lsum;
        const size_t orow = base_o + (size_t)(q0 + s * 16 + lrow) * D_MODEL;
#pragma unroll
        for (int dt = 0; dt < 4; ++dt) {
            bf16x4 ov = bf16x4{(bf16_t)(o_acc[s][dt][0] * inv),
                               (bf16_t)(o_acc[s][dt][1] * inv),
                               (bf16_t)(o_acc[s][dt][2] * inv),
                               (bf16_t)(o_acc[s][dt][3] * inv)};
            *(bf16x4*)&Ctx[orow + dt * 16 + quad * 4] = ov;
        }
    }
}

// --------------------------- residual + layernorm --------------------------
__global__ __launch_bounds__(256) void ln_res_f32in_kernel(
    const float* __restrict__ x, const bf16_t* __restrict__ res,
    const float* __restrict__ g, const float* __restrict__ be,
    bf16_t* __restrict__ out) {
    const int row = blockIdx.x, t = threadIdx.x;
    const size_t base = (size_t)row * D_MODEL;
    float vals[3], sum = 0.f, sq = 0.f;
#pragma unroll
    for (int it = 0; it < 3; ++it) {
        int i = t + it * 256;
        float v = x[base + i] + (float)res[base + i];
        vals[it] = v; sum += v; sq += v * v;
    }
#pragma unroll
    for (int d = 1; d < 64; d <<= 1) { sum += __shfl_xor(sum, d, 64); sq += __shfl_xor(sq, d, 64); }
    __shared__ float ssum[4], ssq[4], s_mu, s_rs;
    if ((t & 63) == 0) { ssum[t >> 6] = sum; ssq[t >> 6] = sq; }
    __syncthreads();
    if (t == 0) {
        float S = ssum[0] + ssum[1] + ssum[2] + ssum[3];
        float Qq = ssq[0] + ssq[1] + ssq[2] + ssq[3];
        float mu = S / D_MODEL;
        s_mu = mu;
        s_rs = rsqrtf(Qq / D_MODEL - mu * mu + 1e-5f);
    }
    __syncthreads();
    const float mu = s_mu, rs = s_rs;
#pragma unroll
    for (int it = 0; it < 3; ++it) {
        int i = t + it * 256;
        out[base + i] = (bf16_t)((vals[it] - mu) * rs * g[i] + be[i]);
    }
}

__global__ __launch_bounds__(256) void ln_res_final_kernel(
    const bf16_t* __restrict__ a, const bf16_t* __restrict__ bfb,
    const float* __restrict__ g, const float* __restrict__ be,
    float* __restrict__ out) {
    const int row = blockIdx.x, t = threadIdx.x;
    const size_t base = (size_t)row * D_MODEL;
    float vals[3], sum = 0.f, sq = 0.f;
#pragma unroll
    for (int it = 0; it < 3; ++it) {
        int i = t + it * 256;
        float v = (float)a[base + i] + (float)bfb[base + i];
        vals[it] = v; sum += v; sq += v * v;
    }
#pragma unroll
    for (int d = 1; d < 64; d <<= 1) { sum += __shfl_xor(sum, d, 64); sq += __shfl_xor(sq, d, 64); }
    __shared__ float ssum[4], ssq[4], s_mu, s_rs;
    if ((t & 63) == 0) { ssum[t >> 6] = sum; ssq[t >> 6] = sq; }
    __syncthreads();
    if (t == 0) {
        float S = ssum[0] + ssum[1] + ssum[2] + ssum[3];
        float Qq = ssq[0] + ssq[1] + ssq[2] + ssq[3];
        float mu = S / D_MODEL;
        s_mu = mu;
        s_rs = rsqrtf(Qq / D_MODEL - mu * mu + 1e-5f);
    }
    __syncthreads();
    const float mu = s_mu, rs = s_rs;
#pragma unroll
    for (int it = 0; it < 3; ++it) {
        int i = t + it * 256;
        out[base + i] = (vals[it] - mu) * rs * g[i] + be[i];
    }
}

// ------------------------------- launcher ----------------------------------
extern "C" void kernel_launch(void* const* d_in, const int* in_sizes, int n_in,
                              void* d_out, int out_size, void* d_ws, size_t ws_size,
                              hipStream_t stream) {
    const float* x    = (const float*)d_in[0];
    const float* wq   = (const float*)d_in[1];
    const float* bq   = (const float*)d_in[2];
    const float* wk   = (const float*)d_in[3];
    const float* bk   = (const float*)d_in[4];
    const float* wv   = (const float*)d_in[5];
    const float* bv   = (const float*)d_in[6];
    const float* wo   = (const float*)d_in[7];
    const float* bo   = (const float*)d_in[8];
    const float* w1   = (const float*)d_in[9];
    const float* b1   = (const float*)d_in[10];
    const float* w2   = (const float*)d_in[11];
    const float* b2   = (const float*)d_in[12];
    const float* g1   = (const float*)d_in[13];
    const float* be1  = (const float*)d_in[14];
    const float* g2   = (const float*)d_in[15];
    const float* be2  = (const float*)d_in[16];
    float* out = (float*)d_out;

    // ---- workspace layout (aliased; ~127.5 MB) ----
    char* ws = (char*)d_ws;
    const size_t SZ_XB   = (size_t)M_ROWS * D_MODEL * 2;
    const size_t SZ_QKV  = (size_t)M_ROWS * LDQKV * 2;
    const size_t SZ_CTX  = SZ_XB;
    const size_t SZ_H    = (size_t)M_ROWS * H_FF * 2;
    const size_t SZ_WQKV = (size_t)LDQKV * D_MODEL * 2;
    const size_t SZ_WO   = (size_t)D_MODEL * D_MODEL * 2;
    const size_t SZ_W1   = (size_t)H_FF * D_MODEL * 2;

    bf16_t* xb    = (bf16_t*)(ws);                    // also n1 after LN1
    bf16_t* qkvb  = (bf16_t*)(ws + SZ_XB);            // also mha out (reuse)
    bf16_t* ctxb  = (bf16_t*)(ws + SZ_XB + SZ_QKV);   // also ffn2 out (reuse)
    bf16_t* hb    = (bf16_t*)(ws + SZ_XB + SZ_QKV + SZ_CTX);
    char*   wsw   = ws + SZ_XB + SZ_QKV + SZ_CTX + SZ_H;
    bf16_t* wqkvb = (bf16_t*)(wsw);
    bf16_t* wob   = (bf16_t*)(wsw + SZ_WQKV);
    bf16_t* w1b   = (bf16_t*)(wsw + SZ_WQKV + SZ_WO);
    bf16_t* w2b   = (bf16_t*)(wsw + SZ_WQKV + SZ_WO + SZ_W1);
    float*  bqkv  = (float*)(wsw + SZ_WQKV + SZ_WO + 2 * SZ_W1);
    bf16_t* mhab  = qkvb;
    bf16_t* n1b   = xb;
    bf16_t* ffb   = ctxb;

    fused_convert_kernel<<<NCONV_V / 256, 256, 0, stream>>>(
        x, wq, wk, wv, wo, w1, w2, xb, wqkvb, wob, w1b, w2b);
    pack_bias_kernel<<<9, 256, 0, stream>>>(bq, bk, bv, bqkv);

    gemm_lds_kernel<128><<<dim3(LDQKV / 128, M_ROWS / 128), 256, 0, stream>>>(
        xb, wqkvb, bqkv, qkvb, M_ROWS, LDQKV, D_MODEL, 0);

    attn_kernel<<<dim3(SEQ / 128, BATCH * N_HEADS), 256, 0, stream>>>(qkvb, ctxb);

    gemm_lds_kernel<64><<<dim3(D_MODEL / 64, M_ROWS / 128), 256, 0, stream>>>(
        ctxb, wob, bo, mhab, M_ROWS, D_MODEL, D_MODEL, 0);

    ln_res_f32in_kernel<<<M_ROWS, 256, 0, stream>>>(x, mhab, g1, be1, n1b);

    gemm_lds_kernel<128><<<dim3(H_FF / 128, M_ROWS / 128), 256, 0, stream>>>(
        n1b, w1b, b1, hb, M_ROWS, H_FF, D_MODEL, 1);

    gemm_lds_kernel<64><<<dim3(D_MODEL / 64, M_ROWS / 128), 256, 0, stream>>>(
        hb, w2b, b2, ffb, M_ROWS, D_MODEL, H_FF, 0);

    ln_res_final_kernel<<<M_ROWS, 256, 0, stream>>>(n1b, ffb, g2, be2, out);
}

// Round 7
// 463.008 us; speedup vs baseline: 1.3170x; 1.0238x over previous
//
#include <hip/hip_runtime.h>
#include <cstdint>
#include <cstddef>

// ---------------------------------------------------------------------------
// Transformer encoder block, bf16 MFMA implementation.
//   x:[2,4096,768] fp32 (+ fp32 weights) -> out fp32 [2,4096,768]
// R14: attn reverted to the R8 structure (2 barriers/tile, reg-staged K+V,
// prefetch issued right after barrier1 -- best measured 144.5us; the R11/
// R12/R13 1-barrier experiments all lost: phase-decoupling hypothesis dead)
// + T1 XCD-aware block swizzle on the attn grid. FETCH=104MB vs ~37MB unique
// showed each K/V panel fetched ~4x: the 32 q-tile blocks sharing one (b,h)
// panel were round-robined over 8 XCDs. Bijective remap (768 = 8 x 96):
// each XCD owns 96 contiguous logical blocks = 3 whole panels -> panel
// fetched by exactly 1 XCD; K/V staging loads become L2 hits, shrinking
// the prefetch-drain stall. GEMM/LN/convert unchanged from R9.
// ---------------------------------------------------------------------------

#define D_MODEL 768
#define N_HEADS 12
#define D_K     64
#define SEQ     4096
#define BATCH   2
#define M_ROWS  (BATCH * SEQ)   // 8192
#define H_FF    3072
#define LDQKV   2304            // packed QKV row pitch

// 0.125 * log2(e): scores come out of MFMA already in log2 domain
#define QSCALE 0.18033688011112042f

typedef __bf16 bf16_t;
typedef __attribute__((ext_vector_type(8))) __bf16 bf16x8;
typedef __attribute__((ext_vector_type(4))) __bf16 bf16x4;
typedef __attribute__((ext_vector_type(2))) __bf16 bf16x2;
typedef __attribute__((ext_vector_type(4))) float  floatx4;
typedef __attribute__((ext_vector_type(4))) short  short4_t;

union bf16x4_cast { bf16x4 h; short4_t s; };

__device__ __forceinline__ float gelu_exact(float x) {
    return 0.5f * x * (1.0f + erff(x * 0.70710678118654752f));
}

#if __has_builtin(__builtin_amdgcn_exp2f)
#define EXP2F(x) __builtin_amdgcn_exp2f(x)
#else
static __device__ __forceinline__ float EXP2F(float x) {
    float r; asm("v_exp_f32 %0, %1" : "=v"(r) : "v"(x)); return r;
}
#endif

// async global->LDS, 16B per lane, dest = wave-uniform base + lane*16
#define GLL16(gp, lp)                                                         \
    __builtin_amdgcn_global_load_lds(                                         \
        (const __attribute__((address_space(1))) void*)(gp),                  \
        (__attribute__((address_space(3))) void*)(lp), 16, 0, 0)

// -------------------------------- convert ----------------------------------
#define NX_V  (6291456 / 4)    // x: 8192*768
#define NW_V  (589824 / 4)     // 768*768
#define NF_V  (2359296 / 4)    // 3072*768
#define NCONV_V (NX_V + 4 * NW_V + 2 * NF_V)   // 3,342,336 vec4s

__global__ __launch_bounds__(256) void fused_convert_kernel(
    const float* __restrict__ x,  const float* __restrict__ wq,
    const float* __restrict__ wk, const float* __restrict__ wv,
    const float* __restrict__ wo, const float* __restrict__ w1,
    const float* __restrict__ w2,
    bf16_t* __restrict__ xb, bf16_t* __restrict__ wqkvb,
    bf16_t* __restrict__ wob, bf16_t* __restrict__ w1b,
    bf16_t* __restrict__ w2b) {
    const int v = blockIdx.x * 256 + threadIdx.x;
    const float* src; bf16_t* dst; int off; float scale = 1.0f;
    if (v < NX_V)                    { src = x;  dst = xb;              off = v; }
    else if (v < NX_V + NW_V)        { src = wq; dst = wqkvb;           off = v - NX_V; scale = QSCALE; }
    else if (v < NX_V + 2 * NW_V)    { src = wk; dst = wqkvb + 589824;  off = v - NX_V - NW_V; }
    else if (v < NX_V + 3 * NW_V)    { src = wv; dst = wqkvb + 1179648; off = v - NX_V - 2 * NW_V; }
    else if (v < NX_V + 4 * NW_V)    { src = wo; dst = wob;             off = v - NX_V - 3 * NW_V; }
    else if (v < NX_V + 4 * NW_V + NF_V) { src = w1; dst = w1b;         off = v - NX_V - 4 * NW_V; }
    else                             { src = w2; dst = w2b;             off = v - NX_V - 4 * NW_V - NF_V; }
    floatx4 f = *(const floatx4*)&src[(size_t)off * 4];
    bf16x4 o = bf16x4{(bf16_t)(f[0] * scale), (bf16_t)(f[1] * scale),
                      (bf16_t)(f[2] * scale), (bf16_t)(f[3] * scale)};
    *(bf16x4*)&dst[(size_t)off * 4] = o;
}

__global__ __launch_bounds__(256) void pack_bias_kernel(
    const float* __restrict__ bq, const float* __restrict__ bk,
    const float* __restrict__ bv, float* __restrict__ dst) {
    int i = blockIdx.x * 256 + threadIdx.x;
    if (i < 768)       dst[i] = bq[i] * QSCALE;
    else if (i < 1536) dst[i] = bk[i - 768];
    else if (i < 2304) dst[i] = bv[i - 1536];
}

// -------------------------------- GEMM -------------------------------------
// C[m,n] = act( sum_k A[m,k]*W[n,k] + bias[n] ).  128xBN tile, BK=64,
// XOR-swizzled LDS (linear GLL16 dest + inverse-swizzled global source col
// + swizzled read slot -- rule #21 involution). Swapped-operand MFMA:
// lane holds C[n..n+3] at one m -> bf16x4 epilogue stores.
template<int BN>   // 128 or 64
__global__ __launch_bounds__(256) void gemm_lds_kernel(
    const bf16_t* __restrict__ A, const bf16_t* __restrict__ W,
    const float* __restrict__ bias, bf16_t* __restrict__ C,
    int M, int N, int K, int act) {

    __shared__ bf16_t As[128 * 64];
    __shared__ bf16_t Bs[BN * 64];

    const int t    = threadIdx.x;
    const int lane = t & 63;
    const int w    = t >> 6;
    const int lrow = lane & 15;
    const int quad = lane >> 4;
    const int n0   = blockIdx.x * BN;
    const int m0   = blockIdx.y * 128;

    constexpr int MI = (BN == 128) ? 4 : 2;
    constexpr int NB = (BN == 128) ? 4 : 2;        // B-tile GLL chunks/wave
    const int wmo = (BN == 128) ? (w >> 1) * 64 : w * 32;
    const int wno = (BN == 128) ? (w & 1) * 64 : 0;

    // staging: chunk = 8 rows x 128B; source k-column pre-swizzled
    const int srow = lane >> 3;                    // row within chunk (0..7)
    const int scol = ((lane & 7) ^ srow) * 8;      // inverse-swizzled k col
    size_t a_g[4];
#pragma unroll
    for (int i = 0; i < 4; ++i)
        a_g[i] = (size_t)(m0 + (w * 4 + i) * 8 + srow) * K + scol;
    size_t b_g[NB];
#pragma unroll
    for (int i = 0; i < NB; ++i)
        b_g[i] = (size_t)(n0 + (w * NB + i) * 8 + srow) * K + scol;

    // fragment-read swizzle: slot = (kk*4+quad) ^ (row&7), row&7 == lrow&7
    const int slot0 = (quad ^ (lrow & 7)) * 8;     // kk=0, in elements
    const int slot1 = slot0 ^ 32;                  // kk=1 (ks+4 -> ^4 slots)

    floatx4 acc[MI][4];
#pragma unroll
    for (int i = 0; i < MI; ++i)
#pragma unroll
        for (int j = 0; j < 4; ++j) acc[i][j] = floatx4{0.f, 0.f, 0.f, 0.f};

    for (int k0 = 0; k0 < K; k0 += 64) {
#pragma unroll
        for (int i = 0; i < 4; ++i)
            GLL16(&A[a_g[i] + k0], &As[(w * 4 + i) * 512]);
#pragma unroll
        for (int i = 0; i < NB; ++i)
            GLL16(&W[b_g[i] + k0], &Bs[(w * NB + i) * 512]);
        __syncthreads();

#pragma unroll
        for (int kk = 0; kk < 2; ++kk) {
            const int off = kk ? slot1 : slot0;
            bf16x8 a[MI], b[4];
#pragma unroll
            for (int i = 0; i < MI; ++i)
                a[i] = *(bf16x8*)&As[(wmo + i * 16 + lrow) * 64 + off];
#pragma unroll
            for (int j = 0; j < 4; ++j)
                b[j] = *(bf16x8*)&Bs[(wno + j * 16 + lrow) * 64 + off];
#pragma unroll
            for (int i = 0; i < MI; ++i)
#pragma unroll
                for (int j = 0; j < 4; ++j)
                    acc[i][j] = __builtin_amdgcn_mfma_f32_16x16x32_bf16(
                        b[j], a[i], acc[i][j], 0, 0, 0);   // C^T fragment
        }
        __syncthreads();
    }

    // epilogue: lane holds n = quad*4+{0..3} at m = lrow (per i,j tile)
#pragma unroll
    for (int i = 0; i < MI; ++i) {
        const int m = m0 + wmo + i * 16 + lrow;
#pragma unroll
        for (int j = 0; j < 4; ++j) {
            const int n = n0 + wno + j * 16 + quad * 4;
            const floatx4 bv = *(const floatx4*)&bias[n];
            float v0 = acc[i][j][0] + bv[0];
            float v1 = acc[i][j][1] + bv[1];
            float v2 = acc[i][j][2] + bv[2];
            float v3 = acc[i][j][3] + bv[3];
            if (act) {
                v0 = gelu_exact(v0); v1 = gelu_exact(v1);
                v2 = gelu_exact(v2); v3 = gelu_exact(v3);
            }
            *(bf16x4*)&C[(size_t)m * N + n] =
                bf16x4{(bf16_t)v0, (bf16_t)v1, (bf16_t)v2, (bf16_t)v3};
        }
    }
}

// ------------------------------ attention ----------------------------------
// Flash-style, fixed-base softmax, deferred row-sum. R8 structure (best
// measured): 2 barriers/tile, reg-staged K+V, prefetch issued right after
// barrier1 so the next barrier's vmcnt drain waits on ~600cyc-old loads.
// R14: 1D grid + bijective XCD swizzle (768 = 8 XCDs x 96): each XCD owns
// 3 complete (b,h) K/V panels -> panel L2-resident on exactly one XCD.
__global__ __launch_bounds__(256, 3) void attn_kernel(
    const bf16_t* __restrict__ QKV, bf16_t* __restrict__ Ctx) {

    __shared__ bf16_t Ks[64 * 72];        // 9216 B  [key][d] pitch 72
    __shared__ bf16_t Vt[64 * 72];        // 9216 B  [d][key^vsw(d)] pitch 72

    const int t    = threadIdx.x;
    const int lane = t & 63;
    const int w    = t >> 6;
    const int lrow = lane & 15;
    const int quad = lane >> 4;

    // bijective XCD remap: consecutive hardware ids round-robin over XCDs;
    // nid gives XCD k the contiguous range [96k, 96k+96) = 3 whole panels.
    const int nid = ((int)blockIdx.x & 7) * 96 + ((int)blockIdx.x >> 3);
    const int qt  = nid & 31;              // q-tile 0..31
    const int bh  = nid >> 5;              // (b,h) 0..23
    const int b   = bh / N_HEADS;
    const int h   = bh % N_HEADS;
    const int q0  = qt * 128 + w * 32;
    const size_t base_q = ((size_t)b * SEQ) * LDQKV + h * D_K;
    const size_t base_k = base_q + 768;
    const size_t base_v = base_q + 1536;
    const size_t base_o = ((size_t)b * SEQ) * D_MODEL + h * D_K;

    // Q fragments (B operand of S^T = K*Q^T: n=q=lane&15, k=d).
    bf16x8 qf[2][2];
#pragma unroll
    for (int s = 0; s < 2; ++s) {
        const size_t qrow = base_q + (size_t)(q0 + s * 16 + lrow) * LDQKV + quad * 8;
        qf[s][0] = *(const bf16x8*)&QKV[qrow];
        qf[s][1] = *(const bf16x8*)&QKV[qrow + 32];
    }

    float l_part[2] = {0.f, 0.f};
    floatx4 o_acc[2][4];
#pragma unroll
    for (int s = 0; s < 2; ++s)
#pragma unroll
        for (int d = 0; d < 4; ++d) o_acc[s][d] = floatx4{0.f, 0.f, 0.f, 0.f};

    // staging assignments
    const int skey = t >> 2;                       // Ks: key 0..63
    const int sch  = t & 3;                        //     d-chunk 0..3
    const int kp   = t >> 3;                       // Vt: key pair 0..31
    const int sch8 = t & 7;                        //     d-chunk-of-8 0..7
    const int vcol = ((2 * kp) & 63) ^ (sch8 << 3);

    // ---- prologue: stage tile 0 into registers ----
    const size_t gk0 = base_k + (size_t)skey * LDQKV + sch * 8;
    const size_t gv0 = base_v + (size_t)(2 * kp) * LDQKV + sch8 * 8;
    bf16x8 kv0 = *(const bf16x8*)&QKV[gk0];
    bf16x8 kv1 = *(const bf16x8*)&QKV[gk0 + 32];
    bf16x8 vv0 = *(const bf16x8*)&QKV[gv0];
    bf16x8 vv1 = *(const bf16x8*)&QKV[gv0 + LDQKV];

    for (int k0 = 0; k0 < SEQ; k0 += 64) {
        // ---- write staged tile regs -> LDS ----
        *(bf16x8*)&Ks[skey * 72 + sch * 8]      = kv0;
        *(bf16x8*)&Ks[skey * 72 + sch * 8 + 32] = kv1;
#pragma unroll
        for (int j = 0; j < 8; ++j)
            *(bf16x2*)&Vt[(sch8 * 8 + j) * 72 + vcol] = bf16x2{vv0[j], vv1[j]};
        __syncthreads();

        // ---- prefetch next tile into regs (latency hides under compute) ----
        if (k0 + 64 < SEQ) {
            const size_t gk = gk0 + (size_t)(k0 + 64) * LDQKV;
            const size_t gv = gv0 + (size_t)(k0 + 64) * LDQKV;
            kv0 = *(const bf16x8*)&QKV[gk];
            kv1 = *(const bf16x8*)&QKV[gk + 32];
            vv0 = *(const bf16x8*)&QKV[gv];
            vv1 = *(const bf16x8*)&QKV[gv + LDQKV];
        }

        __builtin_amdgcn_s_setprio(1);
        // ---- S^T = K Q^T (k32), exp2 -> P kept in registers ----
        short4_t p[2][4];
#pragma unroll
        for (int kt = 0; kt < 4; ++kt) {
            bf16x8 ka0 = *(bf16x8*)&Ks[(kt * 16 + lrow) * 72 + quad * 8];
            bf16x8 ka1 = *(bf16x8*)&Ks[(kt * 16 + lrow) * 72 + 32 + quad * 8];
            floatx4 z = floatx4{0.f, 0.f, 0.f, 0.f};
#pragma unroll
            for (int s = 0; s < 2; ++s) {
                floatx4 st = __builtin_amdgcn_mfma_f32_16x16x32_bf16(ka0, qf[s][0], z, 0, 0, 0);
                st = __builtin_amdgcn_mfma_f32_16x16x32_bf16(ka1, qf[s][1], st, 0, 0, 0);
                float p0 = EXP2F(st[0]), p1 = EXP2F(st[1]);
                float p2 = EXP2F(st[2]), p3 = EXP2F(st[3]);
                l_part[s] += (p0 + p1) + (p2 + p3);
                bf16x4_cast pc;
                pc.h = bf16x4{(bf16_t)p0, (bf16_t)p1, (bf16_t)p2, (bf16_t)p3};
                p[s][kt] = pc.s;
            }
        }

        // ---- O^T += V^T P^T (k16): A = V^T b64 frag, B = P from registers --
#pragma unroll
        for (int dt = 0; dt < 4; ++dt) {
            const int d   = dt * 16 + lrow;
            const int swv = ((d >> 3) & 7) << 3;
#pragma unroll
            for (int kc = 0; kc < 4; ++kc) {
                bf16x4_cast ac;
                ac.h = *(bf16x4*)&Vt[d * 72 + ((kc * 16 + quad * 4) ^ swv)];
                o_acc[0][dt] = __builtin_amdgcn_mfma_f32_16x16x16bf16_1k(
                    ac.s, p[0][kc], o_acc[0][dt], 0, 0, 0);
                o_acc[1][dt] = __builtin_amdgcn_mfma_f32_16x16x16bf16_1k(
                    ac.s, p[1][kc], o_acc[1][dt], 0, 0, 0);
            }
        }
        __builtin_amdgcn_s_setprio(0);
        __syncthreads();   // protect Ks/Vt before next staging
    }

    // ---- reduce l across quads + normalize + packed b64 stores ----
    // O^T C-layout: lane holds q = lrow (matches l), d = 16dt + 4quad + r.
#pragma unroll
    for (int s = 0; s < 2; ++s) {
        float lsum = l_part[s];
        lsum += __shfl_xor(lsum, 16, 64);
        lsum += __shfl_xor(lsum, 32, 64);
        const float inv = 1.0f / lsum;
        const size_t orow = base_o + (size_t)(q0 + s * 16 + lrow) * D_MODEL;
#pragma unroll
        for (int dt = 0; dt < 4; ++dt) {
            bf16x4 ov = bf16x4{(bf16_t)(o_acc[s][dt][0] * inv),
                               (bf16_t)(o_acc[s][dt][1] * inv),
                               (bf16_t)(o_acc[s][dt][2] * inv),
                               (bf16_t)(o_acc[s][dt][3] * inv)};
            *(bf16x4*)&Ctx[orow + dt * 16 + quad * 4] = ov;
        }
    }
}

// --------------------------- residual + layernorm --------------------------
__global__ __launch_bounds__(256) void ln_res_f32in_kernel(
    const float* __restrict__ x, const bf16_t* __restrict__ res,
    const float* __restrict__ g, const float* __restrict__ be,
    bf16_t* __restrict__ out) {
    const int row = blockIdx.x, t = threadIdx.x;
    const size_t base = (size_t)row * D_MODEL;
    float vals[3], sum = 0.f, sq = 0.f;
#pragma unroll
    for (int it = 0; it < 3; ++it) {
        int i = t + it * 256;
        float v = x[base + i] + (float)res[base + i];
        vals[it] = v; sum += v; sq += v * v;
    }
#pragma unroll
    for (int d = 1; d < 64; d <<= 1) { sum += __shfl_xor(sum, d, 64); sq += __shfl_xor(sq, d, 64); }
    __shared__ float ssum[4], ssq[4], s_mu, s_rs;
    if ((t & 63) == 0) { ssum[t >> 6] = sum; ssq[t >> 6] = sq; }
    __syncthreads();
    if (t == 0) {
        float S = ssum[0] + ssum[1] + ssum[2] + ssum[3];
        float Qq = ssq[0] + ssq[1] + ssq[2] + ssq[3];
        float mu = S / D_MODEL;
        s_mu = mu;
        s_rs = rsqrtf(Qq / D_MODEL - mu * mu + 1e-5f);
    }
    __syncthreads();
    const float mu = s_mu, rs = s_rs;
#pragma unroll
    for (int it = 0; it < 3; ++it) {
        int i = t + it * 256;
        out[base + i] = (bf16_t)((vals[it] - mu) * rs * g[i] + be[i]);
    }
}

__global__ __launch_bounds__(256) void ln_res_final_kernel(
    const bf16_t* __restrict__ a, const bf16_t* __restrict__ bfb,
    const float* __restrict__ g, const float* __restrict__ be,
    float* __restrict__ out) {
    const int row = blockIdx.x, t = threadIdx.x;
    const size_t base = (size_t)row * D_MODEL;
    float vals[3], sum = 0.f, sq = 0.f;
#pragma unroll
    for (int it = 0; it < 3; ++it) {
        int i = t + it * 256;
        float v = (float)a[base + i] + (float)bfb[base + i];
        vals[it] = v; sum += v; sq += v * v;
    }
#pragma unroll
    for (int d = 1; d < 64; d <<= 1) { sum += __shfl_xor(sum, d, 64); sq += __shfl_xor(sq, d, 64); }
    __shared__ float ssum[4], ssq[4], s_mu, s_rs;
    if ((t & 63) == 0) { ssum[t >> 6] = sum; ssq[t >> 6] = sq; }
    __syncthreads();
    if (t == 0) {
        float S = ssum[0] + ssum[1] + ssum[2] + ssum[3];
        float Qq = ssq[0] + ssq[1] + ssq[2] + ssq[3];
        float mu = S / D_MODEL;
        s_mu = mu;
        s_rs = rsqrtf(Qq / D_MODEL - mu * mu + 1e-5f);
    }
    __syncthreads();
    const float mu = s_mu, rs = s_rs;
#pragma unroll
    for (int it = 0; it < 3; ++it) {
        int i = t + it * 256;
        out[base + i] = (vals[it] - mu) * rs * g[i] + be[i];
    }
}

// ------------------------------- launcher ----------------------------------
extern "C" void kernel_launch(void* const* d_in, const int* in_sizes, int n_in,
                              void* d_out, int out_size, void* d_ws, size_t ws_size,
                              hipStream_t stream) {
    const float* x    = (const float*)d_in[0];
    const float* wq   = (const float*)d_in[1];
    const float* bq   = (const float*)d_in[2];
    const float* wk   = (const float*)d_in[3];
    const float* bk   = (const float*)d_in[4];
    const float* wv   = (const float*)d_in[5];
    const float* bv   = (const float*)d_in[6];
    const float* wo   = (const float*)d_in[7];
    const float* bo   = (const float*)d_in[8];
    const float* w1   = (const float*)d_in[9];
    const float* b1   = (const float*)d_in[10];
    const float* w2   = (const float*)d_in[11];
    const float* b2   = (const float*)d_in[12];
    const float* g1   = (const float*)d_in[13];
    const float* be1  = (const float*)d_in[14];
    const float* g2   = (const float*)d_in[15];
    const float* be2  = (const float*)d_in[16];
    float* out = (float*)d_out;

    // ---- workspace layout (aliased; ~127.5 MB) ----
    char* ws = (char*)d_ws;
    const size_t SZ_XB   = (size_t)M_ROWS * D_MODEL * 2;
    const size_t SZ_QKV  = (size_t)M_ROWS * LDQKV * 2;
    const size_t SZ_CTX  = SZ_XB;
    const size_t SZ_H    = (size_t)M_ROWS * H_FF * 2;
    const size_t SZ_WQKV = (size_t)LDQKV * D_MODEL * 2;
    const size_t SZ_WO   = (size_t)D_MODEL * D_MODEL * 2;
    const size_t SZ_W1   = (size_t)H_FF * D_MODEL * 2;

    bf16_t* xb    = (bf16_t*)(ws);                    // also n1 after LN1
    bf16_t* qkvb  = (bf16_t*)(ws + SZ_XB);            // also mha out (reuse)
    bf16_t* ctxb  = (bf16_t*)(ws + SZ_XB + SZ_QKV);   // also ffn2 out (reuse)
    bf16_t* hb    = (bf16_t*)(ws + SZ_XB + SZ_QKV + SZ_CTX);
    char*   wsw   = ws + SZ_XB + SZ_QKV + SZ_CTX + SZ_H;
    bf16_t* wqkvb = (bf16_t*)(wsw);
    bf16_t* wob   = (bf16_t*)(wsw + SZ_WQKV);
    bf16_t* w1b   = (bf16_t*)(wsw + SZ_WQKV + SZ_WO);
    bf16_t* w2b   = (bf16_t*)(wsw + SZ_WQKV + SZ_WO + SZ_W1);
    float*  bqkv  = (float*)(wsw + SZ_WQKV + SZ_WO + 2 * SZ_W1);
    bf16_t* mhab  = qkvb;
    bf16_t* n1b   = xb;
    bf16_t* ffb   = ctxb;

    fused_convert_kernel<<<NCONV_V / 256, 256, 0, stream>>>(
        x, wq, wk, wv, wo, w1, w2, xb, wqkvb, wob, w1b, w2b);
    pack_bias_kernel<<<9, 256, 0, stream>>>(bq, bk, bv, bqkv);

    gemm_lds_kernel<128><<<dim3(LDQKV / 128, M_ROWS / 128), 256, 0, stream>>>(
        xb, wqkvb, bqkv, qkvb, M_ROWS, LDQKV, D_MODEL, 0);

    attn_kernel<<<dim3(SEQ / 128 * BATCH * N_HEADS), 256, 0, stream>>>(qkvb, ctxb);

    gemm_lds_kernel<64><<<dim3(D_MODEL / 64, M_ROWS / 128), 256, 0, stream>>>(
        ctxb, wob, bo, mhab, M_ROWS, D_MODEL, D_MODEL, 0);

    ln_res_f32in_kernel<<<M_ROWS, 256, 0, stream>>>(x, mhab, g1, be1, n1b);

    gemm_lds_kernel<128><<<dim3(H_FF / 128, M_ROWS / 128), 256, 0, stream>>>(
        n1b, w1b, b1, hb, M_ROWS, H_FF, D_MODEL, 1);

    gemm_lds_kernel<64><<<dim3(D_MODEL / 64, M_ROWS / 128), 256, 0, stream>>>(
        hb, w2b, b2, ffb, M_ROWS, D_MODEL, H_FF, 0);

    ln_res_final_kernel<<<M_ROWS, 256, 0, stream>>>(n1b, ffb, g2, be2, out);
}

// Round 8
// 436.223 us; speedup vs baseline: 1.3979x; 1.0614x over previous
//
#include <hip/hip_runtime.h>
#include <cstdint>
#include <cstddef>

// ---------------------------------------------------------------------------
// Transformer encoder block, bf16 MFMA implementation.
//   x:[2,4096,768] fp32 (+ fp32 weights) -> out fp32 [2,4096,768]
// R15: R14 + XCD-aware bijective swizzle on ALL GEMM grids (m-major).
// R14 proved the mechanism on attn: panel ownership per XCD cut FETCH
// 104->18.5MB and dur 157->136.6us. GEMMs have the same pathology: x-fastest
// dispatch round-robins same-m blocks over 8 XCDs, so A-panels are
// re-fetched per XCD and every K-step's GLL16 barrier-drain waits on HBM
// (~900cyc) instead of L2 (~200cyc). Remap: flat=(by*gx+bx);
// nid=(flat&7)*(T/8)+(flat>>3); m0=nid/gx, n0=nid%gx -> each XCD owns 8
// contiguous m-rows x all n (A-slab fetched once/XCD, W L2-resident).
// All grids divide by 8 (1152/768/1536/768). attn/LN/convert unchanged.
// ---------------------------------------------------------------------------

#define D_MODEL 768
#define N_HEADS 12
#define D_K     64
#define SEQ     4096
#define BATCH   2
#define M_ROWS  (BATCH * SEQ)   // 8192
#define H_FF    3072
#define LDQKV   2304            // packed QKV row pitch

// 0.125 * log2(e): scores come out of MFMA already in log2 domain
#define QSCALE 0.18033688011112042f

typedef __bf16 bf16_t;
typedef __attribute__((ext_vector_type(8))) __bf16 bf16x8;
typedef __attribute__((ext_vector_type(4))) __bf16 bf16x4;
typedef __attribute__((ext_vector_type(2))) __bf16 bf16x2;
typedef __attribute__((ext_vector_type(4))) float  floatx4;
typedef __attribute__((ext_vector_type(4))) short  short4_t;

union bf16x4_cast { bf16x4 h; short4_t s; };

__device__ __forceinline__ float gelu_exact(float x) {
    return 0.5f * x * (1.0f + erff(x * 0.70710678118654752f));
}

#if __has_builtin(__builtin_amdgcn_exp2f)
#define EXP2F(x) __builtin_amdgcn_exp2f(x)
#else
static __device__ __forceinline__ float EXP2F(float x) {
    float r; asm("v_exp_f32 %0, %1" : "=v"(r) : "v"(x)); return r;
}
#endif

// async global->LDS, 16B per lane, dest = wave-uniform base + lane*16
#define GLL16(gp, lp)                                                         \
    __builtin_amdgcn_global_load_lds(                                         \
        (const __attribute__((address_space(1))) void*)(gp),                  \
        (__attribute__((address_space(3))) void*)(lp), 16, 0, 0)

// -------------------------------- convert ----------------------------------
#define NX_V  (6291456 / 4)    // x: 8192*768
#define NW_V  (589824 / 4)     // 768*768
#define NF_V  (2359296 / 4)    // 3072*768
#define NCONV_V (NX_V + 4 * NW_V + 2 * NF_V)   // 3,342,336 vec4s

__global__ __launch_bounds__(256) void fused_convert_kernel(
    const float* __restrict__ x,  const float* __restrict__ wq,
    const float* __restrict__ wk, const float* __restrict__ wv,
    const float* __restrict__ wo, const float* __restrict__ w1,
    const float* __restrict__ w2,
    bf16_t* __restrict__ xb, bf16_t* __restrict__ wqkvb,
    bf16_t* __restrict__ wob, bf16_t* __restrict__ w1b,
    bf16_t* __restrict__ w2b) {
    const int v = blockIdx.x * 256 + threadIdx.x;
    const float* src; bf16_t* dst; int off; float scale = 1.0f;
    if (v < NX_V)                    { src = x;  dst = xb;              off = v; }
    else if (v < NX_V + NW_V)        { src = wq; dst = wqkvb;           off = v - NX_V; scale = QSCALE; }
    else if (v < NX_V + 2 * NW_V)    { src = wk; dst = wqkvb + 589824;  off = v - NX_V - NW_V; }
    else if (v < NX_V + 3 * NW_V)    { src = wv; dst = wqkvb + 1179648; off = v - NX_V - 2 * NW_V; }
    else if (v < NX_V + 4 * NW_V)    { src = wo; dst = wob;             off = v - NX_V - 3 * NW_V; }
    else if (v < NX_V + 4 * NW_V + NF_V) { src = w1; dst = w1b;         off = v - NX_V - 4 * NW_V; }
    else                             { src = w2; dst = w2b;             off = v - NX_V - 4 * NW_V - NF_V; }
    floatx4 f = *(const floatx4*)&src[(size_t)off * 4];
    bf16x4 o = bf16x4{(bf16_t)(f[0] * scale), (bf16_t)(f[1] * scale),
                      (bf16_t)(f[2] * scale), (bf16_t)(f[3] * scale)};
    *(bf16x4*)&dst[(size_t)off * 4] = o;
}

__global__ __launch_bounds__(256) void pack_bias_kernel(
    const float* __restrict__ bq, const float* __restrict__ bk,
    const float* __restrict__ bv, float* __restrict__ dst) {
    int i = blockIdx.x * 256 + threadIdx.x;
    if (i < 768)       dst[i] = bq[i] * QSCALE;
    else if (i < 1536) dst[i] = bk[i - 768];
    else if (i < 2304) dst[i] = bv[i - 1536];
}

// -------------------------------- GEMM -------------------------------------
// C[m,n] = act( sum_k A[m,k]*W[n,k] + bias[n] ).  128xBN tile, BK=64,
// XOR-swizzled LDS (linear GLL16 dest + inverse-swizzled global source col
// + swizzled read slot -- rule #21 involution). Swapped-operand MFMA:
// lane holds C[n..n+3] at one m -> bf16x4 epilogue stores.
// R15: XCD-aware bijective block remap, m-major (see header).
template<int BN>   // 128 or 64
__global__ __launch_bounds__(256) void gemm_lds_kernel(
    const bf16_t* __restrict__ A, const bf16_t* __restrict__ W,
    const float* __restrict__ bias, bf16_t* __restrict__ C,
    int M, int N, int K, int act) {

    __shared__ bf16_t As[128 * 64];
    __shared__ bf16_t Bs[BN * 64];

    const int t    = threadIdx.x;
    const int lane = t & 63;
    const int w    = t >> 6;
    const int lrow = lane & 15;
    const int quad = lane >> 4;

    // XCD swizzle: each XCD owns T/8 contiguous logical ids = 8 whole m-rows
    const int T    = (int)(gridDim.x * gridDim.y);
    const int flat = (int)(blockIdx.y * gridDim.x + blockIdx.x);
    const int nid  = (flat & 7) * (T >> 3) + (flat >> 3);
    const int n0   = (nid % (int)gridDim.x) * BN;
    const int m0   = (nid / (int)gridDim.x) * 128;

    constexpr int MI = (BN == 128) ? 4 : 2;
    constexpr int NB = (BN == 128) ? 4 : 2;        // B-tile GLL chunks/wave
    const int wmo = (BN == 128) ? (w >> 1) * 64 : w * 32;
    const int wno = (BN == 128) ? (w & 1) * 64 : 0;

    // staging: chunk = 8 rows x 128B; source k-column pre-swizzled
    const int srow = lane >> 3;                    // row within chunk (0..7)
    const int scol = ((lane & 7) ^ srow) * 8;      // inverse-swizzled k col
    size_t a_g[4];
#pragma unroll
    for (int i = 0; i < 4; ++i)
        a_g[i] = (size_t)(m0 + (w * 4 + i) * 8 + srow) * K + scol;
    size_t b_g[NB];
#pragma unroll
    for (int i = 0; i < NB; ++i)
        b_g[i] = (size_t)(n0 + (w * NB + i) * 8 + srow) * K + scol;

    // fragment-read swizzle: slot = (kk*4+quad) ^ (row&7), row&7 == lrow&7
    const int slot0 = (quad ^ (lrow & 7)) * 8;     // kk=0, in elements
    const int slot1 = slot0 ^ 32;                  // kk=1 (ks+4 -> ^4 slots)

    floatx4 acc[MI][4];
#pragma unroll
    for (int i = 0; i < MI; ++i)
#pragma unroll
        for (int j = 0; j < 4; ++j) acc[i][j] = floatx4{0.f, 0.f, 0.f, 0.f};

    for (int k0 = 0; k0 < K; k0 += 64) {
#pragma unroll
        for (int i = 0; i < 4; ++i)
            GLL16(&A[a_g[i] + k0], &As[(w * 4 + i) * 512]);
#pragma unroll
        for (int i = 0; i < NB; ++i)
            GLL16(&W[b_g[i] + k0], &Bs[(w * NB + i) * 512]);
        __syncthreads();

#pragma unroll
        for (int kk = 0; kk < 2; ++kk) {
            const int off = kk ? slot1 : slot0;
            bf16x8 a[MI], b[4];
#pragma unroll
            for (int i = 0; i < MI; ++i)
                a[i] = *(bf16x8*)&As[(wmo + i * 16 + lrow) * 64 + off];
#pragma unroll
            for (int j = 0; j < 4; ++j)
                b[j] = *(bf16x8*)&Bs[(wno + j * 16 + lrow) * 64 + off];
#pragma unroll
            for (int i = 0; i < MI; ++i)
#pragma unroll
                for (int j = 0; j < 4; ++j)
                    acc[i][j] = __builtin_amdgcn_mfma_f32_16x16x32_bf16(
                        b[j], a[i], acc[i][j], 0, 0, 0);   // C^T fragment
        }
        __syncthreads();
    }

    // epilogue: lane holds n = quad*4+{0..3} at m = lrow (per i,j tile)
#pragma unroll
    for (int i = 0; i < MI; ++i) {
        const int m = m0 + wmo + i * 16 + lrow;
#pragma unroll
        for (int j = 0; j < 4; ++j) {
            const int n = n0 + wno + j * 16 + quad * 4;
            const floatx4 bv = *(const floatx4*)&bias[n];
            float v0 = acc[i][j][0] + bv[0];
            float v1 = acc[i][j][1] + bv[1];
            float v2 = acc[i][j][2] + bv[2];
            float v3 = acc[i][j][3] + bv[3];
            if (act) {
                v0 = gelu_exact(v0); v1 = gelu_exact(v1);
                v2 = gelu_exact(v2); v3 = gelu_exact(v3);
            }
            *(bf16x4*)&C[(size_t)m * N + n] =
                bf16x4{(bf16_t)v0, (bf16_t)v1, (bf16_t)v2, (bf16_t)v3};
        }
    }
}

// ------------------------------ attention ----------------------------------
// Flash-style, fixed-base softmax, deferred row-sum. R8 structure (best
// measured): 2 barriers/tile, reg-staged K+V, prefetch issued right after
// barrier1 so the next barrier's vmcnt drain waits on ~600cyc-old loads.
// R14: 1D grid + bijective XCD swizzle (768 = 8 XCDs x 96): each XCD owns
// 3 complete (b,h) K/V panels -> panel L2-resident on exactly one XCD.
// (Verified: FETCH 104->18.5MB, dur 157->136.6us.)
__global__ __launch_bounds__(256, 3) void attn_kernel(
    const bf16_t* __restrict__ QKV, bf16_t* __restrict__ Ctx) {

    __shared__ bf16_t Ks[64 * 72];        // 9216 B  [key][d] pitch 72
    __shared__ bf16_t Vt[64 * 72];        // 9216 B  [d][key^vsw(d)] pitch 72

    const int t    = threadIdx.x;
    const int lane = t & 63;
    const int w    = t >> 6;
    const int lrow = lane & 15;
    const int quad = lane >> 4;

    // bijective XCD remap: consecutive hardware ids round-robin over XCDs;
    // nid gives XCD k the contiguous range [96k, 96k+96) = 3 whole panels.
    const int nid = ((int)blockIdx.x & 7) * 96 + ((int)blockIdx.x >> 3);
    const int qt  = nid & 31;              // q-tile 0..31
    const int bh  = nid >> 5;              // (b,h) 0..23
    const int b   = bh / N_HEADS;
    const int h   = bh % N_HEADS;
    const int q0  = qt * 128 + w * 32;
    const size_t base_q = ((size_t)b * SEQ) * LDQKV + h * D_K;
    const size_t base_k = base_q + 768;
    const size_t base_v = base_q + 1536;
    const size_t base_o = ((size_t)b * SEQ) * D_MODEL + h * D_K;

    // Q fragments (B operand of S^T = K*Q^T: n=q=lane&15, k=d).
    bf16x8 qf[2][2];
#pragma unroll
    for (int s = 0; s < 2; ++s) {
        const size_t qrow = base_q + (size_t)(q0 + s * 16 + lrow) * LDQKV + quad * 8;
        qf[s][0] = *(const bf16x8*)&QKV[qrow];
        qf[s][1] = *(const bf16x8*)&QKV[qrow + 32];
    }

    float l_part[2] = {0.f, 0.f};
    floatx4 o_acc[2][4];
#pragma unroll
    for (int s = 0; s < 2; ++s)
#pragma unroll
        for (int d = 0; d < 4; ++d) o_acc[s][d] = floatx4{0.f, 0.f, 0.f, 0.f};

    // staging assignments
    const int skey = t >> 2;                       // Ks: key 0..63
    const int sch  = t & 3;                        //     d-chunk 0..3
    const int kp   = t >> 3;                       // Vt: key pair 0..31
    const int sch8 = t & 7;                        //     d-chunk-of-8 0..7
    const int vcol = ((2 * kp) & 63) ^ (sch8 << 3);

    // ---- prologue: stage tile 0 into registers ----
    const size_t gk0 = base_k + (size_t)skey * LDQKV + sch * 8;
    const size_t gv0 = base_v + (size_t)(2 * kp) * LDQKV + sch8 * 8;
    bf16x8 kv0 = *(const bf16x8*)&QKV[gk0];
    bf16x8 kv1 = *(const bf16x8*)&QKV[gk0 + 32];
    bf16x8 vv0 = *(const bf16x8*)&QKV[gv0];
    bf16x8 vv1 = *(const bf16x8*)&QKV[gv0 + LDQKV];

    for (int k0 = 0; k0 < SEQ; k0 += 64) {
        // ---- write staged tile regs -> LDS ----
        *(bf16x8*)&Ks[skey * 72 + sch * 8]      = kv0;
        *(bf16x8*)&Ks[skey * 72 + sch * 8 + 32] = kv1;
#pragma unroll
        for (int j = 0; j < 8; ++j)
            *(bf16x2*)&Vt[(sch8 * 8 + j) * 72 + vcol] = bf16x2{vv0[j], vv1[j]};
        __syncthreads();

        // ---- prefetch next tile into regs (latency hides under compute) ----
        if (k0 + 64 < SEQ) {
            const size_t gk = gk0 + (size_t)(k0 + 64) * LDQKV;
            const size_t gv = gv0 + (size_t)(k0 + 64) * LDQKV;
            kv0 = *(const bf16x8*)&QKV[gk];
            kv1 = *(const bf16x8*)&QKV[gk + 32];
            vv0 = *(const bf16x8*)&QKV[gv];
            vv1 = *(const bf16x8*)&QKV[gv + LDQKV];
        }

        __builtin_amdgcn_s_setprio(1);
        // ---- S^T = K Q^T (k32), exp2 -> P kept in registers ----
        short4_t p[2][4];
#pragma unroll
        for (int kt = 0; kt < 4; ++kt) {
            bf16x8 ka0 = *(bf16x8*)&Ks[(kt * 16 + lrow) * 72 + quad * 8];
            bf16x8 ka1 = *(bf16x8*)&Ks[(kt * 16 + lrow) * 72 + 32 + quad * 8];
            floatx4 z = floatx4{0.f, 0.f, 0.f, 0.f};
#pragma unroll
            for (int s = 0; s < 2; ++s) {
                floatx4 st = __builtin_amdgcn_mfma_f32_16x16x32_bf16(ka0, qf[s][0], z, 0, 0, 0);
                st = __builtin_amdgcn_mfma_f32_16x16x32_bf16(ka1, qf[s][1], st, 0, 0, 0);
                float p0 = EXP2F(st[0]), p1 = EXP2F(st[1]);
                float p2 = EXP2F(st[2]), p3 = EXP2F(st[3]);
                l_part[s] += (p0 + p1) + (p2 + p3);
                bf16x4_cast pc;
                pc.h = bf16x4{(bf16_t)p0, (bf16_t)p1, (bf16_t)p2, (bf16_t)p3};
                p[s][kt] = pc.s;
            }
        }

        // ---- O^T += V^T P^T (k16): A = V^T b64 frag, B = P from registers --
#pragma unroll
        for (int dt = 0; dt < 4; ++dt) {
            const int d   = dt * 16 + lrow;
            const int swv = ((d >> 3) & 7) << 3;
#pragma unroll
            for (int kc = 0; kc < 4; ++kc) {
                bf16x4_cast ac;
                ac.h = *(bf16x4*)&Vt[d * 72 + ((kc * 16 + quad * 4) ^ swv)];
                o_acc[0][dt] = __builtin_amdgcn_mfma_f32_16x16x16bf16_1k(
                    ac.s, p[0][kc], o_acc[0][dt], 0, 0, 0);
                o_acc[1][dt] = __builtin_amdgcn_mfma_f32_16x16x16bf16_1k(
                    ac.s, p[1][kc], o_acc[1][dt], 0, 0, 0);
            }
        }
        __builtin_amdgcn_s_setprio(0);
        __syncthreads();   // protect Ks/Vt before next staging
    }

    // ---- reduce l across quads + normalize + packed b64 stores ----
    // O^T C-layout: lane holds q = lrow (matches l), d = 16dt + 4quad + r.
#pragma unroll
    for (int s = 0; s < 2; ++s) {
        float lsum = l_part[s];
        lsum += __shfl_xor(lsum, 16, 64);
        lsum += __shfl_xor(lsum, 32, 64);
        const float inv = 1.0f / lsum;
        const size_t orow = base_o + (size_t)(q0 + s * 16 + lrow) * D_MODEL;
#pragma unroll
        for (int dt = 0; dt < 4; ++dt) {
            bf16x4 ov = bf16x4{(bf16_t)(o_acc[s][dt][0] * inv),
                               (bf16_t)(o_acc[s][dt][1] * inv),
                               (bf16_t)(o_acc[s][dt][2] * inv),
                               (bf16_t)(o_acc[s][dt][3] * inv)};
            *(bf16x4*)&Ctx[orow + dt * 16 + quad * 4] = ov;
        }
    }
}

// --------------------------- residual + layernorm --------------------------
__global__ __launch_bounds__(256) void ln_res_f32in_kernel(
    const float* __restrict__ x, const bf16_t* __restrict__ res,
    const float* __restrict__ g, const float* __restrict__ be,
    bf16_t* __restrict__ out) {
    const int row = blockIdx.x, t = threadIdx.x;
    const size_t base = (size_t)row * D_MODEL;
    float vals[3], sum = 0.f, sq = 0.f;
#pragma unroll
    for (int it = 0; it < 3; ++it) {
        int i = t + it * 256;
        float v = x[base + i] + (float)res[base + i];
        vals[it] = v; sum += v; sq += v * v;
    }
#pragma unroll
    for (int d = 1; d < 64; d <<= 1) { sum += __shfl_xor(sum, d, 64); sq += __shfl_xor(sq, d, 64); }
    __shared__ float ssum[4], ssq[4], s_mu, s_rs;
    if ((t & 63) == 0) { ssum[t >> 6] = sum; ssq[t >> 6] = sq; }
    __syncthreads();
    if (t == 0) {
        float S = ssum[0] + ssum[1] + ssum[2] + ssum[3];
        float Qq = ssq[0] + ssq[1] + ssq[2] + ssq[3];
        float mu = S / D_MODEL;
        s_mu = mu;
        s_rs = rsqrtf(Qq / D_MODEL - mu * mu + 1e-5f);
    }
    __syncthreads();
    const float mu = s_mu, rs = s_rs;
#pragma unroll
    for (int it = 0; it < 3; ++it) {
        int i = t + it * 256;
        out[base + i] = (bf16_t)((vals[it] - mu) * rs * g[i] + be[i]);
    }
}

__global__ __launch_bounds__(256) void ln_res_final_kernel(
    const bf16_t* __restrict__ a, const bf16_t* __restrict__ bfb,
    const float* __restrict__ g, const float* __restrict__ be,
    float* __restrict__ out) {
    const int row = blockIdx.x, t = threadIdx.x;
    const size_t base = (size_t)row * D_MODEL;
    float vals[3], sum = 0.f, sq = 0.f;
#pragma unroll
    for (int it = 0; it < 3; ++it) {
        int i = t + it * 256;
        float v = (float)a[base + i] + (float)bfb[base + i];
        vals[it] = v; sum += v; sq += v * v;
    }
#pragma unroll
    for (int d = 1; d < 64; d <<= 1) { sum += __shfl_xor(sum, d, 64); sq += __shfl_xor(sq, d, 64); }
    __shared__ float ssum[4], ssq[4], s_mu, s_rs;
    if ((t & 63) == 0) { ssum[t >> 6] = sum; ssq[t >> 6] = sq; }
    __syncthreads();
    if (t == 0) {
        float S = ssum[0] + ssum[1] + ssum[2] + ssum[3];
        float Qq = ssq[0] + ssq[1] + ssq[2] + ssq[3];
        float mu = S / D_MODEL;
        s_mu = mu;
        s_rs = rsqrtf(Qq / D_MODEL - mu * mu + 1e-5f);
    }
    __syncthreads();
    const float mu = s_mu, rs = s_rs;
#pragma unroll
    for (int it = 0; it < 3; ++it) {
        int i = t + it * 256;
        out[base + i] = (vals[it] - mu) * rs * g[i] + be[i];
    }
}

// ------------------------------- launcher ----------------------------------
extern "C" void kernel_launch(void* const* d_in, const int* in_sizes, int n_in,
                              void* d_out, int out_size, void* d_ws, size_t ws_size,
                              hipStream_t stream) {
    const float* x    = (const float*)d_in[0];
    const float* wq   = (const float*)d_in[1];
    const float* bq   = (const float*)d_in[2];
    const float* wk   = (const float*)d_in[3];
    const float* bk   = (const float*)d_in[4];
    const float* wv   = (const float*)d_in[5];
    const float* bv   = (const float*)d_in[6];
    const float* wo   = (const float*)d_in[7];
    const float* bo   = (const float*)d_in[8];
    const float* w1   = (const float*)d_in[9];
    const float* b1   = (const float*)d_in[10];
    const float* w2   = (const float*)d_in[11];
    const float* b2   = (const float*)d_in[12];
    const float* g1   = (const float*)d_in[13];
    const float* be1  = (const float*)d_in[14];
    const float* g2   = (const float*)d_in[15];
    const float* be2  = (const float*)d_in[16];
    float* out = (float*)d_out;

    // ---- workspace layout (aliased; ~127.5 MB) ----
    char* ws = (char*)d_ws;
    const size_t SZ_XB   = (size_t)M_ROWS * D_MODEL * 2;
    const size_t SZ_QKV  = (size_t)M_ROWS * LDQKV * 2;
    const size_t SZ_CTX  = SZ_XB;
    const size_t SZ_H    = (size_t)M_ROWS * H_FF * 2;
    const size_t SZ_WQKV = (size_t)LDQKV * D_MODEL * 2;
    const size_t SZ_WO   = (size_t)D_MODEL * D_MODEL * 2;
    const size_t SZ_W1   = (size_t)H_FF * D_MODEL * 2;

    bf16_t* xb    = (bf16_t*)(ws);                    // also n1 after LN1
    bf16_t* qkvb  = (bf16_t*)(ws + SZ_XB);            // also mha out (reuse)
    bf16_t* ctxb  = (bf16_t*)(ws + SZ_XB + SZ_QKV);   // also ffn2 out (reuse)
    bf16_t* hb    = (bf16_t*)(ws + SZ_XB + SZ_QKV + SZ_CTX);
    char*   wsw   = ws + SZ_XB + SZ_QKV + SZ_CTX + SZ_H;
    bf16_t* wqkvb = (bf16_t*)(wsw);
    bf16_t* wob   = (bf16_t*)(wsw + SZ_WQKV);
    bf16_t* w1b   = (bf16_t*)(wsw + SZ_WQKV + SZ_WO);
    bf16_t* w2b   = (bf16_t*)(wsw + SZ_WQKV + SZ_WO + SZ_W1);
    float*  bqkv  = (float*)(wsw + SZ_WQKV + SZ_WO + 2 * SZ_W1);
    bf16_t* mhab  = qkvb;
    bf16_t* n1b   = xb;
    bf16_t* ffb   = ctxb;

    fused_convert_kernel<<<NCONV_V / 256, 256, 0, stream>>>(
        x, wq, wk, wv, wo, w1, w2, xb, wqkvb, wob, w1b, w2b);
    pack_bias_kernel<<<9, 256, 0, stream>>>(bq, bk, bv, bqkv);

    gemm_lds_kernel<128><<<dim3(LDQKV / 128, M_ROWS / 128), 256, 0, stream>>>(
        xb, wqkvb, bqkv, qkvb, M_ROWS, LDQKV, D_MODEL, 0);

    attn_kernel<<<dim3(SEQ / 128 * BATCH * N_HEADS), 256, 0, stream>>>(qkvb, ctxb);

    gemm_lds_kernel<64><<<dim3(D_MODEL / 64, M_ROWS / 128), 256, 0, stream>>>(
        ctxb, wob, bo, mhab, M_ROWS, D_MODEL, D_MODEL, 0);

    ln_res_f32in_kernel<<<M_ROWS, 256, 0, stream>>>(x, mhab, g1, be1, n1b);

    gemm_lds_kernel<128><<<dim3(H_FF / 128, M_ROWS / 128), 256, 0, stream>>>(
        n1b, w1b, b1, hb, M_ROWS, H_FF, D_MODEL, 1);

    gemm_lds_kernel<64><<<dim3(D_MODEL / 64, M_ROWS / 128), 256, 0, stream>>>(
        hb, w2b, b2, ffb, M_ROWS, D_MODEL, H_FF, 0);

    ln_res_final_kernel<<<M_ROWS, 256, 0, stream>>>(n1b, ffb, g2, be2, out);
}